// Round 2
// baseline (395.954 us; speedup 1.0000x reference)
//
#include <hip/hip_runtime.h>
#include <hip/hip_bf16.h>
#include <cstddef>

// Problem constants
#define BSZ 8
#define T_  8
#define L_  196
#define D_  192
#define E_  192
#define C_  1536   // E*T
#define N_  16
#define K_  4
#define R_  96

// ---------------- Kernel 1: in_proj GEMM ----------------
// xz[b,e,t,l] = sum_d hidden[b,t,l,d] * W[e,d]
#define BM 64
#define BN 64
#define BKK 32
__global__ __launch_bounds__(256) void k_inproj(
    const float* __restrict__ A,   // hidden, M x 192
    const float* __restrict__ W,   // 384 x 192
    float* __restrict__ xb, float* __restrict__ zb) {
  __shared__ float As[BKK][BM + 4];
  __shared__ float Bs[BKK][BN + 4];
  int tid = threadIdx.x;
  int m0 = blockIdx.x * BM;
  int n0 = blockIdx.y * BN;
  int tx = tid & 15, ty = tid >> 4;
  float acc[4][4] = {};
  for (int k0 = 0; k0 < 192; k0 += BKK) {
#pragma unroll
    for (int i = 0; i < 8; i++) {
      int idx = tid + i * 256;
      int m = idx >> 5, k = idx & 31;
      As[k][m] = A[(size_t)(m0 + m) * 192 + k0 + k];
    }
#pragma unroll
    for (int i = 0; i < 8; i++) {
      int idx = tid + i * 256;
      int n = idx >> 5, k = idx & 31;
      Bs[k][n] = W[(size_t)(n0 + n) * 192 + k0 + k];
    }
    __syncthreads();
#pragma unroll
    for (int kk = 0; kk < BKK; kk++) {
      float a[4], bb[4];
#pragma unroll
      for (int i = 0; i < 4; i++) a[i] = As[kk][ty * 4 + i];
#pragma unroll
      for (int j = 0; j < 4; j++) bb[j] = Bs[kk][tx * 4 + j];
#pragma unroll
      for (int i = 0; i < 4; i++)
#pragma unroll
        for (int j = 0; j < 4; j++) acc[i][j] += a[i] * bb[j];
    }
    __syncthreads();
  }
#pragma unroll
  for (int i = 0; i < 4; i++) {
    int m = m0 + ty * 4 + i;
    int b = m / (T_ * L_);
    int r = m % (T_ * L_);
    int t = r / L_;
    int l = r % L_;
#pragma unroll
    for (int j = 0; j < 4; j++) {
      int e = n0 + tx * 4 + j;
      float v = acc[i][j];
      if (e < E_) {
        int c = e * T_ + t;
        xb[((size_t)b * C_ + c) * L_ + l] = v;
      } else {
        int c = (e - E_) * T_ + t;
        zb[((size_t)b * C_ + c) * L_ + l] = v;
      }
    }
  }
}

// ---------------- Kernel 2: depthwise causal conv (K=4) + bias + SiLU ----------------
__global__ __launch_bounds__(256) void k_conv(
    const float* __restrict__ xb, const float* __restrict__ conv_w,
    const float* __restrict__ conv_b, float* __restrict__ xc) {
  int idx = blockIdx.x * 256 + threadIdx.x;   // B*C*L = 2408448 exactly
  int l = idx % L_;
  int bc = idx / L_;
  int c = bc % C_;
  const float* xrow = xb + (size_t)bc * L_;
  const float* w = conv_w + c * K_;
  float acc = conv_b[c];
#pragma unroll
  for (int k = 0; k < K_; k++) {
    int ll = l - (K_ - 1) + k;
    if (ll >= 0) acc += xrow[ll] * w[k];
  }
  xc[idx] = acc / (1.f + __expf(-acc));
}

// ---------------- Kernel 3: x_dbl GEMM ----------------
__global__ __launch_bounds__(256) void k_xdbl(
    const float* __restrict__ xc, const float* __restrict__ W,  // 128 x 1536
    float* __restrict__ xdbl) {
  int tx = threadIdx.x & 63;
  int ty = threadIdx.x >> 6;
  int l = blockIdx.x * 64 + tx;
  int r0 = blockIdx.y * 4 + ty;
  int r1 = r0 + 64;
  int b = blockIdx.z;
  if (l >= L_) return;
  const float* xcb = xc + (size_t)b * C_ * L_;
  float acc0 = 0.f, acc1 = 0.f;
#pragma unroll 4
  for (int c = 0; c < C_; c++) {
    float v = xcb[(size_t)c * L_ + l];
    acc0 += v * W[(size_t)r0 * C_ + c];
    acc1 += v * W[(size_t)r1 * C_ + c];
  }
  xdbl[((size_t)b * 128 + r0) * L_ + l] = acc0;
  xdbl[((size_t)b * 128 + r1) * L_ + l] = acc1;
}

// ---------------- Kernel 4: delta GEMM + softplus ----------------
__global__ __launch_bounds__(256) void k_delta(
    const float* __restrict__ xdbl, const float* __restrict__ Wdt,  // 1536 x 96
    const float* __restrict__ dt_bias, float* __restrict__ delta) {
  int tx = threadIdx.x & 63;
  int ty = threadIdx.x >> 6;
  int l = blockIdx.x * 64 + tx;
  int c = blockIdx.y * 4 + ty;
  int b = blockIdx.z;
  if (l >= L_) return;
  const float* dt = xdbl + (size_t)b * 128 * L_;  // rows 0..95 are dt
  float acc = 0.f;
#pragma unroll 8
  for (int r = 0; r < R_; r++)
    acc += dt[(size_t)r * L_ + l] * Wdt[(size_t)c * R_ + r];
  acc += dt_bias[c];
  float sp = (acc > 20.f) ? acc : __logf(1.f + __expf(acc));
  delta[((size_t)b * C_ + c) * L_ + l] = sp;
}

// ---------------- Kernel 5a: chunked scan pass 1 ----------------
// Each lane: (b,c,n,chunk). Runs its chunk with h_in=0; stores
// P = prod(dA) and Q = h_end. No cross-lane ops.
template <int CH, int CL>
__global__ __launch_bounds__(256) void k_scan1(
    const float* __restrict__ delta, const float* __restrict__ xc,
    const float* __restrict__ xdbl, const float* __restrict__ A_log,
    float* __restrict__ P, float* __restrict__ Q) {
  int idx = blockIdx.x * 256 + threadIdx.x;   // B*C*CH*16
  int n = idx & 15;
  int pc = idx >> 4;
  int chunk = pc % CH;
  int bc = pc / CH;
  int b = bc / C_;
  int c = bc % C_;
  float a = -__expf(A_log[c * N_ + n]);
  const float* dp = delta + (size_t)bc * L_ + chunk * CL;
  const float* xp = xc + (size_t)bc * L_ + chunk * CL;
  const float* Bp = xdbl + ((size_t)b * 128 + R_ + n) * L_ + chunk * CL;
  float h = 0.f, p = 1.f;
#pragma unroll
  for (int l = 0; l < CL; l++) {
    float d = dp[l];
    float dA = __expf(d * a);
    h = h * dA + d * xp[l] * Bp[l];
    p *= dA;
  }
  P[idx] = p;
  Q[idx] = h;
}

// ---------------- Kernel 5b: carry combine + chunk re-scan + output ----------------
template <int CH, int CL>
__global__ __launch_bounds__(256) void k_scan2(
    const float* __restrict__ delta, const float* __restrict__ xc,
    const float* __restrict__ zb, const float* __restrict__ xdbl,
    const float* __restrict__ A_log, const float* __restrict__ D_param,
    const float* __restrict__ P, const float* __restrict__ Q,
    float* __restrict__ out) {
  int idx = blockIdx.x * 256 + threadIdx.x;   // B*C*CH*16
  int n = idx & 15;
  int pc = idx >> 4;
  int chunk = pc % CH;
  int bc = pc / CH;
  int b = bc / C_;
  int c = bc % C_;
  float a = -__expf(A_log[c * N_ + n]);
  float Dp = D_param[c];
  // carry-in: combine previous chunks' (P,Q)
  float h = 0.f;
  int base = bc * CH * 16 + n;
  for (int k = 0; k < chunk; k++) {
    h = P[base + k * 16] * h + Q[base + k * 16];
  }
  const int l0 = chunk * CL;
  const float* dp = delta + (size_t)bc * L_ + l0;
  const float* xp = xc + (size_t)bc * L_ + l0;
  const float* zp = zb + (size_t)bc * L_ + l0;
  const float* Bp = xdbl + ((size_t)b * 128 + R_ + n) * L_ + l0;
  const float* Cp = xdbl + ((size_t)b * 128 + R_ + N_ + n) * L_ + l0;
  float* op = out + (size_t)bc * L_ + l0;
#pragma unroll
  for (int l = 0; l < CL; l++) {
    float d = dp[l];
    float xv = xp[l];
    float dA = __expf(d * a);
    h = h * dA + d * xv * Bp[l];
    float yv = h * Cp[l];
    yv += __shfl_xor(yv, 1);
    yv += __shfl_xor(yv, 2);
    yv += __shfl_xor(yv, 4);
    yv += __shfl_xor(yv, 8);
    if (n == 0) {
      float zv = zp[l];
      float sz = zv / (1.f + __expf(-zv));
      op[l] = (yv + xv * Dp) * sz;
    }
  }
}

extern "C" void kernel_launch(void* const* d_in, const int* in_sizes, int n_in,
                              void* d_out, int out_size, void* d_ws, size_t ws_size,
                              hipStream_t stream) {
  const float* hidden    = (const float*)d_in[0];
  const float* in_proj_w = (const float*)d_in[1];
  const float* conv_w    = (const float*)d_in[2];
  const float* conv_b    = (const float*)d_in[3];
  const float* x_proj_w  = (const float*)d_in[4];
  const float* dt_proj_w = (const float*)d_in[5];
  const float* dt_bias   = (const float*)d_in[6];
  const float* A_log     = (const float*)d_in[7];
  const float* D_param   = (const float*)d_in[8];
  float* out = (float*)d_out;

  const size_t NBCL = (size_t)BSZ * C_ * L_;   // 2408448
  const size_t NXDBL = (size_t)BSZ * 128 * L_; // 200704
  const size_t NPQ1 = (size_t)BSZ * C_ * N_;   // 196608 (per chunk)
  float* ws = (float*)d_ws;
  float* xb   = ws;                 // pre-conv x  (reused as delta later)
  float* zb   = xb + NBCL;
  float* xc   = zb + NBCL;          // post-conv x
  float* xdbl = xc + NBCL;          // B*128*L
  float* Pbuf = xdbl + NXDBL;
  float* delta = xb;                // reuse: xb dead after conv

  // K1: in_proj GEMM  (M=12544 = 196*64, N=384 = 6*64)
  k_inproj<<<dim3(196, 6), 256, 0, stream>>>(hidden, in_proj_w, xb, zb);
  // K2: conv + silu
  k_conv<<<(int)(NBCL / 256), 256, 0, stream>>>(xb, conv_w, conv_b, xc);
  // K3: x_dbl GEMM
  k_xdbl<<<dim3(4, 16, BSZ), 256, 0, stream>>>(xc, x_proj_w, xdbl);
  // K4: delta GEMM + softplus
  k_delta<<<dim3(4, C_ / 4, BSZ), 256, 0, stream>>>(xdbl, dt_proj_w, dt_bias, delta);

  // K5: chunked scan, chunk count chosen by available workspace
  size_t base_floats = 3 * NBCL + NXDBL;
  size_t avail = ws_size / 4 > base_floats ? ws_size / 4 - base_floats : 0;
  if (avail >= 2 * NPQ1 * 14) {
    float* Qbuf = Pbuf + NPQ1 * 14;
    int nthreads = (int)(NPQ1 * 14);
    k_scan1<14, 14><<<nthreads / 256, 256, 0, stream>>>(delta, xc, xdbl, A_log, Pbuf, Qbuf);
    k_scan2<14, 14><<<nthreads / 256, 256, 0, stream>>>(delta, xc, zb, xdbl, A_log, D_param, Pbuf, Qbuf, out);
  } else if (avail >= 2 * NPQ1 * 7) {
    float* Qbuf = Pbuf + NPQ1 * 7;
    int nthreads = (int)(NPQ1 * 7);
    k_scan1<7, 28><<<nthreads / 256, 256, 0, stream>>>(delta, xc, xdbl, A_log, Pbuf, Qbuf);
    k_scan2<7, 28><<<nthreads / 256, 256, 0, stream>>>(delta, xc, zb, xdbl, A_log, D_param, Pbuf, Qbuf, out);
  } else {
    float* Qbuf = Pbuf + NPQ1 * 2;
    int nthreads = (int)(NPQ1 * 2);
    k_scan1<2, 98><<<nthreads / 256, 256, 0, stream>>>(delta, xc, xdbl, A_log, Pbuf, Qbuf);
    k_scan2<2, 98><<<nthreads / 256, 256, 0, stream>>>(delta, xc, zb, xdbl, A_log, D_param, Pbuf, Qbuf, out);
  }
}

// Round 3
// 283.918 us; speedup vs baseline: 1.3946x; 1.3946x over previous
//
#include <hip/hip_runtime.h>
#include <hip/hip_bf16.h>
#include <cstddef>

// Problem constants
#define BSZ 8
#define T_  8
#define L_  196
#define D_  192
#define E_  192
#define C_  1536   // E*T
#define N_  16
#define K_  4
#define R_  96

// ---------------- Kernel 1: in_proj GEMM ----------------
// xz[b,e,t,l] = sum_d hidden[b,t,l,d] * W[e,d]
#define BM 64
#define BN 64
#define BKK 32
__global__ __launch_bounds__(256) void k_inproj(
    const float* __restrict__ A,   // hidden, M x 192
    const float* __restrict__ W,   // 384 x 192
    float* __restrict__ xb, float* __restrict__ zb) {
  __shared__ float As[BKK][BM + 4];
  __shared__ float Bs[BKK][BN + 4];
  int tid = threadIdx.x;
  int m0 = blockIdx.x * BM;
  int n0 = blockIdx.y * BN;
  int tx = tid & 15, ty = tid >> 4;
  float acc[4][4] = {};
  for (int k0 = 0; k0 < 192; k0 += BKK) {
#pragma unroll
    for (int i = 0; i < 8; i++) {
      int idx = tid + i * 256;
      int m = idx >> 5, k = idx & 31;
      As[k][m] = A[(size_t)(m0 + m) * 192 + k0 + k];
    }
#pragma unroll
    for (int i = 0; i < 8; i++) {
      int idx = tid + i * 256;
      int n = idx >> 5, k = idx & 31;
      Bs[k][n] = W[(size_t)(n0 + n) * 192 + k0 + k];
    }
    __syncthreads();
#pragma unroll
    for (int kk = 0; kk < BKK; kk++) {
      float a[4], bb[4];
#pragma unroll
      for (int i = 0; i < 4; i++) a[i] = As[kk][ty * 4 + i];
#pragma unroll
      for (int j = 0; j < 4; j++) bb[j] = Bs[kk][tx * 4 + j];
#pragma unroll
      for (int i = 0; i < 4; i++)
#pragma unroll
        for (int j = 0; j < 4; j++) acc[i][j] += a[i] * bb[j];
    }
    __syncthreads();
  }
#pragma unroll
  for (int i = 0; i < 4; i++) {
    int m = m0 + ty * 4 + i;
    int b = m / (T_ * L_);
    int r = m % (T_ * L_);
    int t = r / L_;
    int l = r % L_;
#pragma unroll
    for (int j = 0; j < 4; j++) {
      int e = n0 + tx * 4 + j;
      float v = acc[i][j];
      if (e < E_) {
        int c = e * T_ + t;
        xb[((size_t)b * C_ + c) * L_ + l] = v;
      } else {
        int c = (e - E_) * T_ + t;
        zb[((size_t)b * C_ + c) * L_ + l] = v;
      }
    }
  }
}

// ---------------- Kernel 2: depthwise causal conv (K=4) + bias + SiLU ----------------
__global__ __launch_bounds__(256) void k_conv(
    const float* __restrict__ xb, const float* __restrict__ conv_w,
    const float* __restrict__ conv_b, float* __restrict__ xc) {
  int idx = blockIdx.x * 256 + threadIdx.x;   // B*C*L = 2408448 exactly
  int l = idx % L_;
  int bc = idx / L_;
  int c = bc % C_;
  const float* xrow = xb + (size_t)bc * L_;
  const float* w = conv_w + c * K_;
  float acc = conv_b[c];
#pragma unroll
  for (int k = 0; k < K_; k++) {
    int ll = l - (K_ - 1) + k;
    if (ll >= 0) acc += xrow[ll] * w[k];
  }
  xc[idx] = acc / (1.f + __expf(-acc));
}

// ---------------- Kernel 3: x_dbl GEMM ----------------
// dt rows (0..95) -> xdbl[b][r][l]; B rows (96..111) -> Bt[b][l][n];
// C rows (112..127) -> Ct[b][l][n]   (n contiguous for the scan)
__global__ __launch_bounds__(256) void k_xdbl(
    const float* __restrict__ xc, const float* __restrict__ W,  // 128 x 1536
    float* __restrict__ xdbl, float* __restrict__ Bt, float* __restrict__ Ct) {
  int tx = threadIdx.x & 63;
  int ty = threadIdx.x >> 6;
  int l = blockIdx.x * 64 + tx;
  int r0 = blockIdx.y * 4 + ty;      // in [0,64)
  int r1 = r0 + 64;                  // in [64,128)
  int b = blockIdx.z;
  if (l >= L_) return;
  const float* xcb = xc + (size_t)b * C_ * L_;
  float acc0 = 0.f, acc1 = 0.f;
#pragma unroll 4
  for (int c = 0; c < C_; c++) {
    float v = xcb[(size_t)c * L_ + l];
    acc0 += v * W[(size_t)r0 * C_ + c];
    acc1 += v * W[(size_t)r1 * C_ + c];
  }
  xdbl[((size_t)b * 96 + r0) * L_ + l] = acc0;
  if (r1 < 96) {
    xdbl[((size_t)b * 96 + r1) * L_ + l] = acc1;
  } else if (r1 < 96 + N_) {
    Bt[((size_t)b * L_ + l) * N_ + (r1 - 96)] = acc1;
  } else {
    Ct[((size_t)b * L_ + l) * N_ + (r1 - 96 - N_)] = acc1;
  }
}

// ---------------- Kernel 4: delta GEMM + softplus ----------------
__global__ __launch_bounds__(256) void k_delta(
    const float* __restrict__ xdbl, const float* __restrict__ Wdt,  // 1536 x 96
    const float* __restrict__ dt_bias, float* __restrict__ delta) {
  int tx = threadIdx.x & 63;
  int ty = threadIdx.x >> 6;
  int l = blockIdx.x * 64 + tx;
  int c = blockIdx.y * 4 + ty;
  int b = blockIdx.z;
  if (l >= L_) return;
  const float* dt = xdbl + (size_t)b * 96 * L_;
  float acc = 0.f;
#pragma unroll 8
  for (int r = 0; r < R_; r++)
    acc += dt[(size_t)r * L_ + l] * Wdt[(size_t)c * R_ + r];
  acc += dt_bias[c];
  float sp = (acc > 20.f) ? acc : __logf(1.f + __expf(acc));
  delta[((size_t)b * C_ + c) * L_ + l] = sp;
}

// ---------------- Kernel 5a: chunked scan pass 1 ----------------
// lane = (b,c,chunk,nl) with nl in [0,4); each lane owns 4 states.
// Runs its chunk with h_in=0; stores P=prod(dA) and Q=h_end as float4.
template <int CH, int CL>
__global__ __launch_bounds__(256) void k_scan1(
    const float* __restrict__ delta, const float* __restrict__ xc,
    const float* __restrict__ Bt, const float* __restrict__ A_log,
    float4* __restrict__ P, float4* __restrict__ Q) {
  int idx = blockIdx.x * 256 + threadIdx.x;   // B*C*CH*4
  int nl = idx & 3;
  int pc = idx >> 2;
  int chunk = pc % CH;
  int bc = pc / CH;
  int b = bc / C_;
  int c = bc % C_;
  float4 a;
  a.x = -__expf(A_log[c * N_ + nl * 4 + 0]);
  a.y = -__expf(A_log[c * N_ + nl * 4 + 1]);
  a.z = -__expf(A_log[c * N_ + nl * 4 + 2]);
  a.w = -__expf(A_log[c * N_ + nl * 4 + 3]);
  const float* dp = delta + (size_t)bc * L_ + chunk * CL;
  const float* xp = xc + (size_t)bc * L_ + chunk * CL;
  const float* Btp = Bt + ((size_t)b * L_ + chunk * CL) * N_ + nl * 4;
  float4 h = {0.f, 0.f, 0.f, 0.f};
  float4 p = {1.f, 1.f, 1.f, 1.f};
#pragma unroll
  for (int l = 0; l < CL; l++) {
    float d = dp[l];
    float du = d * xp[l];
    float4 Bv = *(const float4*)(Btp + (size_t)l * N_);
    float ex, ey, ez, ew;
    ex = __expf(d * a.x); ey = __expf(d * a.y);
    ez = __expf(d * a.z); ew = __expf(d * a.w);
    h.x = h.x * ex + du * Bv.x; p.x *= ex;
    h.y = h.y * ey + du * Bv.y; p.y *= ey;
    h.z = h.z * ez + du * Bv.z; p.z *= ez;
    h.w = h.w * ew + du * Bv.w; p.w *= ew;
  }
  P[idx] = p;
  Q[idx] = h;
}

// ---------------- Kernel 5b: carry combine + chunk re-scan + output ----------------
template <int CH, int CL>
__global__ __launch_bounds__(256) void k_scan2(
    const float* __restrict__ delta, const float* __restrict__ xc,
    const float* __restrict__ zb, const float* __restrict__ Bt,
    const float* __restrict__ Ct, const float* __restrict__ A_log,
    const float* __restrict__ D_param,
    const float4* __restrict__ P, const float4* __restrict__ Q,
    float* __restrict__ out) {
  int idx = blockIdx.x * 256 + threadIdx.x;   // B*C*CH*4
  int nl = idx & 3;
  int pc = idx >> 2;
  int chunk = pc % CH;
  int bc = pc / CH;
  int b = bc / C_;
  int c = bc % C_;
  float4 a;
  a.x = -__expf(A_log[c * N_ + nl * 4 + 0]);
  a.y = -__expf(A_log[c * N_ + nl * 4 + 1]);
  a.z = -__expf(A_log[c * N_ + nl * 4 + 2]);
  a.w = -__expf(A_log[c * N_ + nl * 4 + 3]);
  float Dp = D_param[c];
  // carry-in: combine previous chunks' (P,Q)
  float4 h = {0.f, 0.f, 0.f, 0.f};
  size_t base = (size_t)bc * CH * 4 + nl;
  for (int k = 0; k < chunk; k++) {
    float4 pk = P[base + (size_t)k * 4];
    float4 qk = Q[base + (size_t)k * 4];
    h.x = pk.x * h.x + qk.x;
    h.y = pk.y * h.y + qk.y;
    h.z = pk.z * h.z + qk.z;
    h.w = pk.w * h.w + qk.w;
  }
  const int l0 = chunk * CL;
  const float* dp = delta + (size_t)bc * L_ + l0;
  const float* xp = xc + (size_t)bc * L_ + l0;
  const float* zp = zb + (size_t)bc * L_ + l0;
  const float* Btp = Bt + ((size_t)b * L_ + l0) * N_ + nl * 4;
  const float* Ctp = Ct + ((size_t)b * L_ + l0) * N_ + nl * 4;
  float* op = out + (size_t)bc * L_ + l0;
#pragma unroll
  for (int l = 0; l < CL; l++) {
    float d = dp[l];
    float xv = xp[l];
    float du = d * xv;
    float4 Bv = *(const float4*)(Btp + (size_t)l * N_);
    float4 Cv = *(const float4*)(Ctp + (size_t)l * N_);
    float ex, ey, ez, ew;
    ex = __expf(d * a.x); ey = __expf(d * a.y);
    ez = __expf(d * a.z); ew = __expf(d * a.w);
    h.x = h.x * ex + du * Bv.x;
    h.y = h.y * ey + du * Bv.y;
    h.z = h.z * ez + du * Bv.z;
    h.w = h.w * ew + du * Bv.w;
    float yv = h.x * Cv.x + h.y * Cv.y + h.z * Cv.z + h.w * Cv.w;
    yv += __shfl_xor(yv, 1);
    yv += __shfl_xor(yv, 2);
    if (nl == 0) {
      float zv = zp[l];
      float sz = zv / (1.f + __expf(-zv));
      op[l] = (yv + xv * Dp) * sz;
    }
  }
}

extern "C" void kernel_launch(void* const* d_in, const int* in_sizes, int n_in,
                              void* d_out, int out_size, void* d_ws, size_t ws_size,
                              hipStream_t stream) {
  const float* hidden    = (const float*)d_in[0];
  const float* in_proj_w = (const float*)d_in[1];
  const float* conv_w    = (const float*)d_in[2];
  const float* conv_b    = (const float*)d_in[3];
  const float* x_proj_w  = (const float*)d_in[4];
  const float* dt_proj_w = (const float*)d_in[5];
  const float* dt_bias   = (const float*)d_in[6];
  const float* A_log     = (const float*)d_in[7];
  const float* D_param   = (const float*)d_in[8];
  float* out = (float*)d_out;

  const size_t NBCL  = (size_t)BSZ * C_ * L_;   // 2408448
  const size_t NDT   = (size_t)BSZ * 96 * L_;   // 150528
  const size_t NBT   = (size_t)BSZ * L_ * N_;   // 25088
  const size_t NPQ1  = (size_t)BSZ * C_ * N_;   // 196608 floats (per chunk)
  float* ws = (float*)d_ws;
  float* xb    = ws;                 // pre-conv x  (reused as delta later)
  float* zb    = xb + NBCL;
  float* xc    = zb + NBCL;          // post-conv x
  float* xdbl  = xc + NBCL;          // dt rows only: B*96*L
  float* BtArr = xdbl + NDT;
  float* CtArr = BtArr + NBT;
  float* Pbuf  = CtArr + NBT;
  float* delta = xb;                 // reuse: xb dead after conv

  // K1: in_proj GEMM  (M=12544 = 196*64, N=384 = 6*64)
  k_inproj<<<dim3(196, 6), 256, 0, stream>>>(hidden, in_proj_w, xb, zb);
  // K2: conv + silu
  k_conv<<<(int)(NBCL / 256), 256, 0, stream>>>(xb, conv_w, conv_b, xc);
  // K3: x_dbl GEMM (+ B/C transpose)
  k_xdbl<<<dim3(4, 16, BSZ), 256, 0, stream>>>(xc, x_proj_w, xdbl, BtArr, CtArr);
  // K4: delta GEMM + softplus
  k_delta<<<dim3(4, C_ / 4, BSZ), 256, 0, stream>>>(xdbl, dt_proj_w, dt_bias, delta);

  // K5: chunked scan, chunk count chosen by available workspace
  size_t base_floats = 3 * NBCL + NDT + 2 * NBT;
  size_t avail = ws_size / 4 > base_floats ? ws_size / 4 - base_floats : 0;
  if (avail >= 2 * NPQ1 * 14) {
    float4* P4 = (float4*)Pbuf;
    float4* Q4 = (float4*)(Pbuf + NPQ1 * 14);
    int nthreads = (int)(BSZ * C_ * 14 * 4);   // 688128
    k_scan1<14, 14><<<nthreads / 256, 256, 0, stream>>>(delta, xc, BtArr, A_log, P4, Q4);
    k_scan2<14, 14><<<nthreads / 256, 256, 0, stream>>>(delta, xc, zb, BtArr, CtArr, A_log, D_param, P4, Q4, out);
  } else if (avail >= 2 * NPQ1 * 7) {
    float4* P4 = (float4*)Pbuf;
    float4* Q4 = (float4*)(Pbuf + NPQ1 * 7);
    int nthreads = (int)(BSZ * C_ * 7 * 4);    // 344064
    k_scan1<7, 28><<<nthreads / 256, 256, 0, stream>>>(delta, xc, BtArr, A_log, P4, Q4);
    k_scan2<7, 28><<<nthreads / 256, 256, 0, stream>>>(delta, xc, zb, BtArr, CtArr, A_log, D_param, P4, Q4, out);
  } else {
    float4* P4 = (float4*)Pbuf;
    float4* Q4 = (float4*)(Pbuf + NPQ1 * 2);
    int nthreads = (int)(BSZ * C_ * 2 * 4);    // 98304
    k_scan1<2, 98><<<nthreads / 256, 256, 0, stream>>>(delta, xc, BtArr, A_log, P4, Q4);
    k_scan2<2, 98><<<nthreads / 256, 256, 0, stream>>>(delta, xc, zb, BtArr, CtArr, A_log, D_param, P4, Q4, out);
  }
}

// Round 4
// 221.711 us; speedup vs baseline: 1.7859x; 1.2806x over previous
//
#include <hip/hip_runtime.h>
#include <hip/hip_bf16.h>
#include <cstddef>

// Problem constants
#define BSZ 8
#define T_  8
#define L_  196
#define D_  192
#define E_  192
#define C_  1536   // E*T
#define N_  16
#define K_  4
#define R_  96

// ---------------- Kernel 1: in_proj GEMM ----------------
// xz[b,e,t,l] = sum_d hidden[b,t,l,d] * W[e,d]
#define BM 64
#define BN 64
#define BKK 32
__global__ __launch_bounds__(256) void k_inproj(
    const float* __restrict__ A,   // hidden, M x 192
    const float* __restrict__ W,   // 384 x 192
    float* __restrict__ xb, float* __restrict__ zb) {
  __shared__ float As[BKK][BM + 4];
  __shared__ float Bs[BKK][BN + 4];
  int tid = threadIdx.x;
  int m0 = blockIdx.x * BM;
  int n0 = blockIdx.y * BN;
  int tx = tid & 15, ty = tid >> 4;
  float acc[4][4] = {};
  for (int k0 = 0; k0 < 192; k0 += BKK) {
#pragma unroll
    for (int i = 0; i < 8; i++) {
      int idx = tid + i * 256;
      int m = idx >> 5, k = idx & 31;
      As[k][m] = A[(size_t)(m0 + m) * 192 + k0 + k];
    }
#pragma unroll
    for (int i = 0; i < 8; i++) {
      int idx = tid + i * 256;
      int n = idx >> 5, k = idx & 31;
      Bs[k][n] = W[(size_t)(n0 + n) * 192 + k0 + k];
    }
    __syncthreads();
#pragma unroll
    for (int kk = 0; kk < BKK; kk++) {
      float a[4], bb[4];
#pragma unroll
      for (int i = 0; i < 4; i++) a[i] = As[kk][ty * 4 + i];
#pragma unroll
      for (int j = 0; j < 4; j++) bb[j] = Bs[kk][tx * 4 + j];
#pragma unroll
      for (int i = 0; i < 4; i++)
#pragma unroll
        for (int j = 0; j < 4; j++) acc[i][j] += a[i] * bb[j];
    }
    __syncthreads();
  }
#pragma unroll
  for (int i = 0; i < 4; i++) {
    int m = m0 + ty * 4 + i;
    int b = m / (T_ * L_);
    int r = m % (T_ * L_);
    int t = r / L_;
    int l = r % L_;
#pragma unroll
    for (int j = 0; j < 4; j++) {
      int e = n0 + tx * 4 + j;
      float v = acc[i][j];
      if (e < E_) {
        int c = e * T_ + t;
        xb[((size_t)b * C_ + c) * L_ + l] = v;
      } else {
        int c = (e - E_) * T_ + t;
        zb[((size_t)b * C_ + c) * L_ + l] = v;
      }
    }
  }
}

// ---------------- Kernel 2: depthwise causal conv (K=4) + bias + SiLU ----------------
__global__ __launch_bounds__(256) void k_conv(
    const float* __restrict__ xb, const float* __restrict__ conv_w,
    const float* __restrict__ conv_b, float* __restrict__ xc) {
  int idx = blockIdx.x * 256 + threadIdx.x;   // B*C*L = 2408448 exactly
  int l = idx % L_;
  int bc = idx / L_;
  int c = bc % C_;
  const float* xrow = xb + (size_t)bc * L_;
  const float* w = conv_w + c * K_;
  float acc = conv_b[c];
#pragma unroll
  for (int k = 0; k < K_; k++) {
    int ll = l - (K_ - 1) + k;
    if (ll >= 0) acc += xrow[ll] * w[k];
  }
  xc[idx] = acc / (1.f + __expf(-acc));
}

// ---------------- Kernel 3a: W transpose (128x1536 -> [c][128]) ----------------
__global__ __launch_bounds__(256) void k_wtrans(
    const float* __restrict__ W, float* __restrict__ Wt) {
  int idx = blockIdx.x * 256 + threadIdx.x;  // 128*1536 = 196608
  int r = idx / 1536;
  int c = idx - r * 1536;
  Wt[(size_t)c * 128 + r] = W[idx];
}

// ---------------- Kernel 3b: split-K x_dbl GEMM ----------------
// part[kc][b][l][128] = sum_{c in chunk kc} xc[b][c][l] * Wt[c][r]
__global__ __launch_bounds__(256) void k_xdblsplit(
    const float* __restrict__ xc, const float* __restrict__ Wt,
    float* __restrict__ part) {
  int tx = threadIdx.x & 63;
  int ty = threadIdx.x >> 6;
  int l0 = blockIdx.x * 8 + ty;     // blockIdx.x in [0,25)
  int l1 = l0 + 4;
  int kc = blockIdx.y;
  int b  = blockIdx.z;
  bool has1 = l1 < L_;              // l0 < 196 always (max 195)
  const float* xp = xc + ((size_t)b * C_ + kc * 192) * L_ + l0;
  const float* wp = Wt + (size_t)kc * 192 * 128 + tx;
  float a00 = 0.f, a01 = 0.f, a10 = 0.f, a11 = 0.f;
#pragma unroll 4
  for (int c = 0; c < 192; c++) {
    float w0 = wp[c * 128];
    float w1 = wp[c * 128 + 64];
    float x0 = xp[(size_t)c * L_];
    float x1 = has1 ? xp[(size_t)c * L_ + 4] : 0.f;
    a00 += x0 * w0; a01 += x0 * w1;
    a10 += x1 * w0; a11 += x1 * w1;
  }
  size_t o0 = (((size_t)kc * 8 + b) * L_ + l0) * 128 + tx;
  part[o0] = a00; part[o0 + 64] = a01;
  if (has1) {
    size_t o1 = (((size_t)kc * 8 + b) * L_ + l1) * 128 + tx;
    part[o1] = a10; part[o1 + 64] = a11;
  }
}

// ---------------- Kernel 3c: reduce partials -> dt [b][96][l], Bt/Ct [b][l][16] ----------------
__global__ __launch_bounds__(256) void k_xreduce(
    const float* __restrict__ part, float* __restrict__ xdbl,
    float* __restrict__ Bt, float* __restrict__ Ct) {
  int tx = threadIdx.x & 63;
  int ty = threadIdx.x >> 6;
  int l = blockIdx.x * 4 + ty;      // 49*4 = 196 exactly
  int b = blockIdx.y;
  size_t o = ((size_t)b * L_ + l) * 128 + tx;
  float v0 = 0.f, v1 = 0.f;
#pragma unroll
  for (int kc = 0; kc < 8; kc++) {
    v0 += part[(size_t)kc * (8 * L_ * 128) + o];
    v1 += part[(size_t)kc * (8 * L_ * 128) + o + 64];
  }
  int r1 = tx + 64;
  xdbl[((size_t)b * 96 + tx) * L_ + l] = v0;
  if (r1 < 96) {
    xdbl[((size_t)b * 96 + r1) * L_ + l] = v1;
  } else if (r1 < 96 + N_) {
    Bt[((size_t)b * L_ + l) * N_ + (r1 - 96)] = v1;
  } else {
    Ct[((size_t)b * L_ + l) * N_ + (r1 - 96 - N_)] = v1;
  }
}

// ---------------- Kernel 3-mono (fallback, small ws): x_dbl GEMM ----------------
__global__ __launch_bounds__(256) void k_xdbl_mono(
    const float* __restrict__ xc, const float* __restrict__ W,  // 128 x 1536
    float* __restrict__ xdbl, float* __restrict__ Bt, float* __restrict__ Ct) {
  int tx = threadIdx.x & 63;
  int ty = threadIdx.x >> 6;
  int l = blockIdx.x * 64 + tx;
  int r0 = blockIdx.y * 4 + ty;
  int r1 = r0 + 64;
  int b = blockIdx.z;
  if (l >= L_) return;
  const float* xcb = xc + (size_t)b * C_ * L_;
  float acc0 = 0.f, acc1 = 0.f;
#pragma unroll 4
  for (int c = 0; c < C_; c++) {
    float v = xcb[(size_t)c * L_ + l];
    acc0 += v * W[(size_t)r0 * C_ + c];
    acc1 += v * W[(size_t)r1 * C_ + c];
  }
  xdbl[((size_t)b * 96 + r0) * L_ + l] = acc0;
  if (r1 < 96) {
    xdbl[((size_t)b * 96 + r1) * L_ + l] = acc1;
  } else if (r1 < 96 + N_) {
    Bt[((size_t)b * L_ + l) * N_ + (r1 - 96)] = acc1;
  } else {
    Ct[((size_t)b * L_ + l) * N_ + (r1 - 96 - N_)] = acc1;
  }
}

// ---------------- Kernel 4: delta GEMM + softplus ----------------
__global__ __launch_bounds__(256) void k_delta(
    const float* __restrict__ xdbl, const float* __restrict__ Wdt,  // 1536 x 96
    const float* __restrict__ dt_bias, float* __restrict__ delta) {
  int tx = threadIdx.x & 63;
  int ty = threadIdx.x >> 6;
  int l = blockIdx.x * 64 + tx;
  int c = blockIdx.y * 4 + ty;
  int b = blockIdx.z;
  if (l >= L_) return;
  const float* dt = xdbl + (size_t)b * 96 * L_;
  float acc = 0.f;
#pragma unroll 8
  for (int r = 0; r < R_; r++)
    acc += dt[(size_t)r * L_ + l] * Wdt[(size_t)c * R_ + r];
  acc += dt_bias[c];
  float sp = (acc > 20.f) ? acc : __logf(1.f + __expf(acc));
  delta[((size_t)b * C_ + c) * L_ + l] = sp;
}

// ---------------- Kernel 5a: chunked scan pass 1 ----------------
template <int CH, int CL>
__global__ __launch_bounds__(256) void k_scan1(
    const float* __restrict__ delta, const float* __restrict__ xc,
    const float* __restrict__ Bt, const float* __restrict__ A_log,
    float4* __restrict__ P, float4* __restrict__ Q) {
  int idx = blockIdx.x * 256 + threadIdx.x;   // B*C*CH*4
  int nl = idx & 3;
  int pc = idx >> 2;
  int chunk = pc % CH;
  int bc = pc / CH;
  int b = bc / C_;
  int c = bc % C_;
  float4 a;
  a.x = -__expf(A_log[c * N_ + nl * 4 + 0]);
  a.y = -__expf(A_log[c * N_ + nl * 4 + 1]);
  a.z = -__expf(A_log[c * N_ + nl * 4 + 2]);
  a.w = -__expf(A_log[c * N_ + nl * 4 + 3]);
  const float* dp = delta + (size_t)bc * L_ + chunk * CL;
  const float* xp = xc + (size_t)bc * L_ + chunk * CL;
  const float* Btp = Bt + ((size_t)b * L_ + chunk * CL) * N_ + nl * 4;
  float4 h = {0.f, 0.f, 0.f, 0.f};
  float4 p = {1.f, 1.f, 1.f, 1.f};
#pragma unroll
  for (int l = 0; l < CL; l++) {
    float d = dp[l];
    float du = d * xp[l];
    float4 Bv = *(const float4*)(Btp + (size_t)l * N_);
    float ex, ey, ez, ew;
    ex = __expf(d * a.x); ey = __expf(d * a.y);
    ez = __expf(d * a.z); ew = __expf(d * a.w);
    h.x = h.x * ex + du * Bv.x; p.x *= ex;
    h.y = h.y * ey + du * Bv.y; p.y *= ey;
    h.z = h.z * ez + du * Bv.z; p.z *= ez;
    h.w = h.w * ew + du * Bv.w; p.w *= ew;
  }
  P[idx] = p;
  Q[idx] = h;
}

// ---------------- Kernel 5b: carry combine + chunk re-scan + output ----------------
template <int CH, int CL>
__global__ __launch_bounds__(256) void k_scan2(
    const float* __restrict__ delta, const float* __restrict__ xc,
    const float* __restrict__ zb, const float* __restrict__ Bt,
    const float* __restrict__ Ct, const float* __restrict__ A_log,
    const float* __restrict__ D_param,
    const float4* __restrict__ P, const float4* __restrict__ Q,
    float* __restrict__ out) {
  int idx = blockIdx.x * 256 + threadIdx.x;   // B*C*CH*4
  int nl = idx & 3;
  int pc = idx >> 2;
  int chunk = pc % CH;
  int bc = pc / CH;
  int b = bc / C_;
  int c = bc % C_;
  float4 a;
  a.x = -__expf(A_log[c * N_ + nl * 4 + 0]);
  a.y = -__expf(A_log[c * N_ + nl * 4 + 1]);
  a.z = -__expf(A_log[c * N_ + nl * 4 + 2]);
  a.w = -__expf(A_log[c * N_ + nl * 4 + 3]);
  float Dp = D_param[c];
  float4 h = {0.f, 0.f, 0.f, 0.f};
  size_t base = (size_t)bc * CH * 4 + nl;
  for (int k = 0; k < chunk; k++) {
    float4 pk = P[base + (size_t)k * 4];
    float4 qk = Q[base + (size_t)k * 4];
    h.x = pk.x * h.x + qk.x;
    h.y = pk.y * h.y + qk.y;
    h.z = pk.z * h.z + qk.z;
    h.w = pk.w * h.w + qk.w;
  }
  const int l0 = chunk * CL;
  const float* dp = delta + (size_t)bc * L_ + l0;
  const float* xp = xc + (size_t)bc * L_ + l0;
  const float* zp = zb + (size_t)bc * L_ + l0;
  const float* Btp = Bt + ((size_t)b * L_ + l0) * N_ + nl * 4;
  const float* Ctp = Ct + ((size_t)b * L_ + l0) * N_ + nl * 4;
  float* op = out + (size_t)bc * L_ + l0;
#pragma unroll
  for (int l = 0; l < CL; l++) {
    float d = dp[l];
    float xv = xp[l];
    float du = d * xv;
    float4 Bv = *(const float4*)(Btp + (size_t)l * N_);
    float4 Cv = *(const float4*)(Ctp + (size_t)l * N_);
    float ex, ey, ez, ew;
    ex = __expf(d * a.x); ey = __expf(d * a.y);
    ez = __expf(d * a.z); ew = __expf(d * a.w);
    h.x = h.x * ex + du * Bv.x;
    h.y = h.y * ey + du * Bv.y;
    h.z = h.z * ez + du * Bv.z;
    h.w = h.w * ew + du * Bv.w;
    float yv = h.x * Cv.x + h.y * Cv.y + h.z * Cv.z + h.w * Cv.w;
    yv += __shfl_xor(yv, 1);
    yv += __shfl_xor(yv, 2);
    if (nl == 0) {
      float zv = zp[l];
      float sz = zv / (1.f + __expf(-zv));
      op[l] = (yv + xv * Dp) * sz;
    }
  }
}

extern "C" void kernel_launch(void* const* d_in, const int* in_sizes, int n_in,
                              void* d_out, int out_size, void* d_ws, size_t ws_size,
                              hipStream_t stream) {
  const float* hidden    = (const float*)d_in[0];
  const float* in_proj_w = (const float*)d_in[1];
  const float* conv_w    = (const float*)d_in[2];
  const float* conv_b    = (const float*)d_in[3];
  const float* x_proj_w  = (const float*)d_in[4];
  const float* dt_proj_w = (const float*)d_in[5];
  const float* dt_bias   = (const float*)d_in[6];
  const float* A_log     = (const float*)d_in[7];
  const float* D_param   = (const float*)d_in[8];
  float* out = (float*)d_out;

  const size_t NBCL  = (size_t)BSZ * C_ * L_;    // 2408448
  const size_t NDT   = (size_t)BSZ * 96 * L_;    // 150528
  const size_t NBT   = (size_t)BSZ * L_ * N_;    // 25088
  const size_t NPQ1  = (size_t)BSZ * C_ * N_;    // 196608 floats (per chunk)
  const size_t NPART = (size_t)8 * BSZ * L_ * 128; // 1605632
  const size_t NWT   = (size_t)C_ * 128;         // 196608
  float* ws = (float*)d_ws;
  float* xb    = ws;                 // pre-conv x  (reused as delta later)
  float* zb    = xb + NBCL;
  float* xc    = zb + NBCL;          // post-conv x
  float* xdbl  = xc + NBCL;          // dt rows only: B*96*L
  float* BtArr = xdbl + NDT;
  float* CtArr = BtArr + NBT;
  float* Pbuf  = CtArr + NBT;        // big region: part+Wt, later P/Q
  float* delta = xb;                 // reuse: xb dead after conv

  size_t base_floats = 3 * NBCL + NDT + 2 * NBT;
  size_t avail = ws_size / 4 > base_floats ? ws_size / 4 - base_floats : 0;
  bool split_ok = avail >= NPART + NWT;

  // K1: in_proj GEMM  (M=12544 = 196*64, N=384 = 6*64)
  k_inproj<<<dim3(196, 6), 256, 0, stream>>>(hidden, in_proj_w, xb, zb);
  // K2: conv + silu
  k_conv<<<(int)(NBCL / 256), 256, 0, stream>>>(xb, conv_w, conv_b, xc);

  // K3: x_dbl GEMM (+ B/C transpose)
  if (split_ok) {
    float* part = Pbuf;
    float* Wt   = Pbuf + NPART;
    k_wtrans<<<(int)(NWT / 256), 256, 0, stream>>>(x_proj_w, Wt);
    k_xdblsplit<<<dim3(25, 8, BSZ), 256, 0, stream>>>(xc, Wt, part);
    k_xreduce<<<dim3(49, BSZ), 256, 0, stream>>>(part, xdbl, BtArr, CtArr);
  } else {
    k_xdbl_mono<<<dim3(4, 16, BSZ), 256, 0, stream>>>(xc, x_proj_w, xdbl, BtArr, CtArr);
  }

  // K4: delta GEMM + softplus
  k_delta<<<dim3(4, C_ / 4, BSZ), 256, 0, stream>>>(xdbl, dt_proj_w, dt_bias, delta);

  // K5: chunked scan, chunk count chosen by available workspace
  if (avail >= 2 * NPQ1 * 14) {
    float4* P4 = (float4*)Pbuf;
    float4* Q4 = (float4*)(Pbuf + NPQ1 * 14);
    int nthreads = (int)(BSZ * C_ * 14 * 4);   // 688128
    k_scan1<14, 14><<<nthreads / 256, 256, 0, stream>>>(delta, xc, BtArr, A_log, P4, Q4);
    k_scan2<14, 14><<<nthreads / 256, 256, 0, stream>>>(delta, xc, zb, BtArr, CtArr, A_log, D_param, P4, Q4, out);
  } else if (avail >= 2 * NPQ1 * 7) {
    float4* P4 = (float4*)Pbuf;
    float4* Q4 = (float4*)(Pbuf + NPQ1 * 7);
    int nthreads = (int)(BSZ * C_ * 7 * 4);    // 344064
    k_scan1<7, 28><<<nthreads / 256, 256, 0, stream>>>(delta, xc, BtArr, A_log, P4, Q4);
    k_scan2<7, 28><<<nthreads / 256, 256, 0, stream>>>(delta, xc, zb, BtArr, CtArr, A_log, D_param, P4, Q4, out);
  } else {
    float4* P4 = (float4*)Pbuf;
    float4* Q4 = (float4*)(Pbuf + NPQ1 * 2);
    int nthreads = (int)(BSZ * C_ * 2 * 4);    // 98304
    k_scan1<2, 98><<<nthreads / 256, 256, 0, stream>>>(delta, xc, BtArr, A_log, P4, Q4);
    k_scan2<2, 98><<<nthreads / 256, 256, 0, stream>>>(delta, xc, zb, BtArr, CtArr, A_log, D_param, P4, Q4, out);
  }
}

// Round 5
// 177.278 us; speedup vs baseline: 2.2335x; 1.2506x over previous
//
#include <hip/hip_runtime.h>
#include <hip/hip_bf16.h>
#include <cstddef>

// Problem constants
#define BSZ 8
#define T_  8
#define L_  196
#define D_  192
#define E_  192
#define C_  1536   // E*T
#define N_  16
#define K_  4
#define R_  96

// ---------------- Kernel 1: in_proj GEMM ----------------
// xz[b,e,t,l] = sum_d hidden[b,t,l,d] * W[e,d]
#define BM 64
#define BN 64
#define BKK 32
__global__ __launch_bounds__(256) void k_inproj(
    const float* __restrict__ A,   // hidden, M x 192
    const float* __restrict__ W,   // 384 x 192
    float* __restrict__ xb, float* __restrict__ zb) {
  __shared__ float As[BKK][BM + 4];
  __shared__ float Bs[BKK][BN + 4];
  int tid = threadIdx.x;
  int m0 = blockIdx.x * BM;
  int n0 = blockIdx.y * BN;
  int tx = tid & 15, ty = tid >> 4;
  float acc[4][4] = {};
  for (int k0 = 0; k0 < 192; k0 += BKK) {
#pragma unroll
    for (int i = 0; i < 8; i++) {
      int idx = tid + i * 256;
      int m = idx >> 5, k = idx & 31;
      As[k][m] = A[(size_t)(m0 + m) * 192 + k0 + k];
    }
#pragma unroll
    for (int i = 0; i < 8; i++) {
      int idx = tid + i * 256;
      int n = idx >> 5, k = idx & 31;
      Bs[k][n] = W[(size_t)(n0 + n) * 192 + k0 + k];
    }
    __syncthreads();
#pragma unroll
    for (int kk = 0; kk < BKK; kk++) {
      float a[4], bb[4];
#pragma unroll
      for (int i = 0; i < 4; i++) a[i] = As[kk][ty * 4 + i];
#pragma unroll
      for (int j = 0; j < 4; j++) bb[j] = Bs[kk][tx * 4 + j];
#pragma unroll
      for (int i = 0; i < 4; i++)
#pragma unroll
        for (int j = 0; j < 4; j++) acc[i][j] += a[i] * bb[j];
    }
    __syncthreads();
  }
#pragma unroll
  for (int i = 0; i < 4; i++) {
    int m = m0 + ty * 4 + i;
    int b = m / (T_ * L_);
    int r = m % (T_ * L_);
    int t = r / L_;
    int l = r % L_;
#pragma unroll
    for (int j = 0; j < 4; j++) {
      int e = n0 + tx * 4 + j;
      float v = acc[i][j];
      if (e < E_) {
        int c = e * T_ + t;
        xb[((size_t)b * C_ + c) * L_ + l] = v;
      } else {
        int c = (e - E_) * T_ + t;
        zb[((size_t)b * C_ + c) * L_ + l] = v;
      }
    }
  }
}

// ---------------- Kernel 2: depthwise causal conv (K=4) + bias + SiLU ----------------
__global__ __launch_bounds__(256) void k_conv(
    const float* __restrict__ xb, const float* __restrict__ conv_w,
    const float* __restrict__ conv_b, float* __restrict__ xc) {
  int idx = blockIdx.x * 256 + threadIdx.x;   // B*C*L = 2408448 exactly
  int l = idx % L_;
  int bc = idx / L_;
  int c = bc % C_;
  const float* xrow = xb + (size_t)bc * L_;
  const float* w = conv_w + c * K_;
  float acc = conv_b[c];
#pragma unroll
  for (int k = 0; k < K_; k++) {
    int ll = l - (K_ - 1) + k;
    if (ll >= 0) acc += xrow[ll] * w[k];
  }
  xc[idx] = acc / (1.f + __expf(-acc));
}

// ---------------- Kernel 3a: W transpose (128x1536 -> [c][128]) ----------------
__global__ __launch_bounds__(256) void k_wtrans(
    const float* __restrict__ W, float* __restrict__ Wt) {
  int idx = blockIdx.x * 256 + threadIdx.x;  // 128*1536 = 196608
  int r = idx / 1536;
  int c = idx - r * 1536;
  Wt[(size_t)c * 128 + r] = W[idx];
}

// ---------------- Kernel 3b: split-K x_dbl GEMM ----------------
// part[kc][b][l][128] = sum_{c in chunk kc} xc[b][c][l] * Wt[c][r]
__global__ __launch_bounds__(256) void k_xdblsplit(
    const float* __restrict__ xc, const float* __restrict__ Wt,
    float* __restrict__ part) {
  int tx = threadIdx.x & 63;
  int ty = threadIdx.x >> 6;
  int l0 = blockIdx.x * 8 + ty;     // blockIdx.x in [0,25)
  int l1 = l0 + 4;
  int kc = blockIdx.y;
  int b  = blockIdx.z;
  bool has1 = l1 < L_;              // l0 < 196 always (max 195)
  const float* xp = xc + ((size_t)b * C_ + kc * 192) * L_ + l0;
  const float* wp = Wt + (size_t)kc * 192 * 128 + tx;
  float a00 = 0.f, a01 = 0.f, a10 = 0.f, a11 = 0.f;
#pragma unroll 4
  for (int c = 0; c < 192; c++) {
    float w0 = wp[c * 128];
    float w1 = wp[c * 128 + 64];
    float x0 = xp[(size_t)c * L_];
    float x1 = has1 ? xp[(size_t)c * L_ + 4] : 0.f;
    a00 += x0 * w0; a01 += x0 * w1;
    a10 += x1 * w0; a11 += x1 * w1;
  }
  size_t o0 = (((size_t)kc * 8 + b) * L_ + l0) * 128 + tx;
  part[o0] = a00; part[o0 + 64] = a01;
  if (has1) {
    size_t o1 = (((size_t)kc * 8 + b) * L_ + l1) * 128 + tx;
    part[o1] = a10; part[o1 + 64] = a11;
  }
}

// ---------------- Kernel 3c: reduce partials -> dt [b][96][l], Bt/Ct [b][l][16] ----------------
__global__ __launch_bounds__(256) void k_xreduce(
    const float* __restrict__ part, float* __restrict__ xdbl,
    float* __restrict__ Bt, float* __restrict__ Ct) {
  int tx = threadIdx.x & 63;
  int ty = threadIdx.x >> 6;
  int l = blockIdx.x * 4 + ty;      // 49*4 = 196 exactly
  int b = blockIdx.y;
  size_t o = ((size_t)b * L_ + l) * 128 + tx;
  float v0 = 0.f, v1 = 0.f;
#pragma unroll
  for (int kc = 0; kc < 8; kc++) {
    v0 += part[(size_t)kc * (8 * L_ * 128) + o];
    v1 += part[(size_t)kc * (8 * L_ * 128) + o + 64];
  }
  int r1 = tx + 64;
  xdbl[((size_t)b * 96 + tx) * L_ + l] = v0;
  if (r1 < 96) {
    xdbl[((size_t)b * 96 + r1) * L_ + l] = v1;
  } else if (r1 < 96 + N_) {
    Bt[((size_t)b * L_ + l) * N_ + (r1 - 96)] = v1;
  } else {
    Ct[((size_t)b * L_ + l) * N_ + (r1 - 96 - N_)] = v1;
  }
}

// ---------------- Kernel 3-mono (fallback, small ws): x_dbl GEMM ----------------
__global__ __launch_bounds__(256) void k_xdbl_mono(
    const float* __restrict__ xc, const float* __restrict__ W,  // 128 x 1536
    float* __restrict__ xdbl, float* __restrict__ Bt, float* __restrict__ Ct) {
  int tx = threadIdx.x & 63;
  int ty = threadIdx.x >> 6;
  int l = blockIdx.x * 64 + tx;
  int r0 = blockIdx.y * 4 + ty;
  int r1 = r0 + 64;
  int b = blockIdx.z;
  if (l >= L_) return;
  const float* xcb = xc + (size_t)b * C_ * L_;
  float acc0 = 0.f, acc1 = 0.f;
#pragma unroll 4
  for (int c = 0; c < C_; c++) {
    float v = xcb[(size_t)c * L_ + l];
    acc0 += v * W[(size_t)r0 * C_ + c];
    acc1 += v * W[(size_t)r1 * C_ + c];
  }
  xdbl[((size_t)b * 96 + r0) * L_ + l] = acc0;
  if (r1 < 96) {
    xdbl[((size_t)b * 96 + r1) * L_ + l] = acc1;
  } else if (r1 < 96 + N_) {
    Bt[((size_t)b * L_ + l) * N_ + (r1 - 96)] = acc1;
  } else {
    Ct[((size_t)b * L_ + l) * N_ + (r1 - 96 - N_)] = acc1;
  }
}

// ---------------- Kernel 4: delta GEMM + softplus (LDS-tiled) ----------------
// delta[b,c,l] = softplus(sum_r dtm[b,r,l]*Wdt[c,r] + dt_bias[c])
// M = C = 1536 (c), N = B*L = 1568 flattened (b,l), K = 96 in one shot.
__global__ __launch_bounds__(256) void k_delta_gemm(
    const float* __restrict__ dtm, const float* __restrict__ Wdt,  // 1536 x 96
    const float* __restrict__ dt_bias, float* __restrict__ delta) {
  __shared__ float Ws[96][68];   // Ws[r][i] = Wdt[c0+i][r]
  __shared__ float Ds[96][68];   // Ds[r][j] = dtm[b][r][l], n0+j=(b,l)
  int tid = threadIdx.x;
  int n0 = blockIdx.x * 64;      // flattened (b,l), 25 tiles over 1568
  int c0 = blockIdx.y * 64;
  for (int idx = tid; idx < 64 * 96; idx += 256) {
    int i = idx / 96, r = idx - i * 96;
    Ws[r][i] = Wdt[(size_t)(c0 + i) * 96 + r];
  }
  for (int idx = tid; idx < 96 * 64; idx += 256) {
    int r = idx >> 6, j = idx & 63;
    int n = n0 + j;
    float v = 0.f;
    if (n < BSZ * L_) {
      int b = n / L_, l = n - b * L_;
      v = dtm[((size_t)b * 96 + r) * L_ + l];
    }
    Ds[r][j] = v;
  }
  __syncthreads();
  int tx = tid & 15, ty = tid >> 4;
  float acc[4][4] = {};
#pragma unroll 8
  for (int r = 0; r < 96; r++) {
    float4 av = *(const float4*)&Ws[r][ty * 4];
    float4 bv = *(const float4*)&Ds[r][tx * 4];
    float a_[4] = {av.x, av.y, av.z, av.w};
    float b_[4] = {bv.x, bv.y, bv.z, bv.w};
#pragma unroll
    for (int i = 0; i < 4; i++)
#pragma unroll
      for (int j = 0; j < 4; j++) acc[i][j] += a_[i] * b_[j];
  }
#pragma unroll
  for (int i = 0; i < 4; i++) {
    int c = c0 + ty * 4 + i;
    float bias = dt_bias[c];
#pragma unroll
    for (int j = 0; j < 4; j++) {
      int n = n0 + tx * 4 + j;
      if (n < BSZ * L_) {
        int b = n / L_, l = n - b * L_;
        float v = acc[i][j] + bias;
        float sp = (v > 20.f) ? v : __logf(1.f + __expf(v));
        delta[((size_t)b * C_ + c) * L_ + l] = sp;
      }
    }
  }
}

// ---------------- Kernel 5a: chunked scan pass 1 ----------------
template <int CH, int CL>
__global__ __launch_bounds__(256) void k_scan1(
    const float* __restrict__ delta, const float* __restrict__ xc,
    const float* __restrict__ Bt, const float* __restrict__ A_log,
    float4* __restrict__ P, float4* __restrict__ Q) {
  int idx = blockIdx.x * 256 + threadIdx.x;   // B*C*CH*4
  int nl = idx & 3;
  int pc = idx >> 2;
  int chunk = pc % CH;
  int bc = pc / CH;
  int b = bc / C_;
  int c = bc % C_;
  float4 a;
  a.x = -__expf(A_log[c * N_ + nl * 4 + 0]);
  a.y = -__expf(A_log[c * N_ + nl * 4 + 1]);
  a.z = -__expf(A_log[c * N_ + nl * 4 + 2]);
  a.w = -__expf(A_log[c * N_ + nl * 4 + 3]);
  const float* dp = delta + (size_t)bc * L_ + chunk * CL;
  const float* xp = xc + (size_t)bc * L_ + chunk * CL;
  const float* Btp = Bt + ((size_t)b * L_ + chunk * CL) * N_ + nl * 4;
  float4 h = {0.f, 0.f, 0.f, 0.f};
  float4 p = {1.f, 1.f, 1.f, 1.f};
#pragma unroll
  for (int l = 0; l < CL; l++) {
    float d = dp[l];
    float du = d * xp[l];
    float4 Bv = *(const float4*)(Btp + (size_t)l * N_);
    float ex, ey, ez, ew;
    ex = __expf(d * a.x); ey = __expf(d * a.y);
    ez = __expf(d * a.z); ew = __expf(d * a.w);
    h.x = h.x * ex + du * Bv.x; p.x *= ex;
    h.y = h.y * ey + du * Bv.y; p.y *= ey;
    h.z = h.z * ez + du * Bv.z; p.z *= ez;
    h.w = h.w * ew + du * Bv.w; p.w *= ew;
  }
  P[idx] = p;
  Q[idx] = h;
}

// ---------------- Kernel 5b: carry combine + chunk re-scan + output ----------------
template <int CH, int CL>
__global__ __launch_bounds__(256) void k_scan2(
    const float* __restrict__ delta, const float* __restrict__ xc,
    const float* __restrict__ zb, const float* __restrict__ Bt,
    const float* __restrict__ Ct, const float* __restrict__ A_log,
    const float* __restrict__ D_param,
    const float4* __restrict__ P, const float4* __restrict__ Q,
    float* __restrict__ out) {
  int idx = blockIdx.x * 256 + threadIdx.x;   // B*C*CH*4
  int nl = idx & 3;
  int pc = idx >> 2;
  int chunk = pc % CH;
  int bc = pc / CH;
  int b = bc / C_;
  int c = bc % C_;
  float4 a;
  a.x = -__expf(A_log[c * N_ + nl * 4 + 0]);
  a.y = -__expf(A_log[c * N_ + nl * 4 + 1]);
  a.z = -__expf(A_log[c * N_ + nl * 4 + 2]);
  a.w = -__expf(A_log[c * N_ + nl * 4 + 3]);
  float Dp = D_param[c];
  float4 h = {0.f, 0.f, 0.f, 0.f};
  size_t base = (size_t)bc * CH * 4 + nl;
  for (int k = 0; k < chunk; k++) {
    float4 pk = P[base + (size_t)k * 4];
    float4 qk = Q[base + (size_t)k * 4];
    h.x = pk.x * h.x + qk.x;
    h.y = pk.y * h.y + qk.y;
    h.z = pk.z * h.z + qk.z;
    h.w = pk.w * h.w + qk.w;
  }
  const int l0 = chunk * CL;
  const float* dp = delta + (size_t)bc * L_ + l0;
  const float* xp = xc + (size_t)bc * L_ + l0;
  const float* zp = zb + (size_t)bc * L_ + l0;
  const float* Btp = Bt + ((size_t)b * L_ + l0) * N_ + nl * 4;
  const float* Ctp = Ct + ((size_t)b * L_ + l0) * N_ + nl * 4;
  float* op = out + (size_t)bc * L_ + l0;
#pragma unroll
  for (int l = 0; l < CL; l++) {
    float d = dp[l];
    float xv = xp[l];
    float du = d * xv;
    float4 Bv = *(const float4*)(Btp + (size_t)l * N_);
    float4 Cv = *(const float4*)(Ctp + (size_t)l * N_);
    float ex, ey, ez, ew;
    ex = __expf(d * a.x); ey = __expf(d * a.y);
    ez = __expf(d * a.z); ew = __expf(d * a.w);
    h.x = h.x * ex + du * Bv.x;
    h.y = h.y * ey + du * Bv.y;
    h.z = h.z * ez + du * Bv.z;
    h.w = h.w * ew + du * Bv.w;
    float yv = h.x * Cv.x + h.y * Cv.y + h.z * Cv.z + h.w * Cv.w;
    yv += __shfl_xor(yv, 1);
    yv += __shfl_xor(yv, 2);
    if (nl == 0) {
      float zv = zp[l];
      float sz = zv / (1.f + __expf(-zv));
      op[l] = (yv + xv * Dp) * sz;
    }
  }
}

extern "C" void kernel_launch(void* const* d_in, const int* in_sizes, int n_in,
                              void* d_out, int out_size, void* d_ws, size_t ws_size,
                              hipStream_t stream) {
  const float* hidden    = (const float*)d_in[0];
  const float* in_proj_w = (const float*)d_in[1];
  const float* conv_w    = (const float*)d_in[2];
  const float* conv_b    = (const float*)d_in[3];
  const float* x_proj_w  = (const float*)d_in[4];
  const float* dt_proj_w = (const float*)d_in[5];
  const float* dt_bias   = (const float*)d_in[6];
  const float* A_log     = (const float*)d_in[7];
  const float* D_param   = (const float*)d_in[8];
  float* out = (float*)d_out;

  const size_t NBCL  = (size_t)BSZ * C_ * L_;    // 2408448
  const size_t NDT   = (size_t)BSZ * 96 * L_;    // 150528
  const size_t NBT   = (size_t)BSZ * L_ * N_;    // 25088
  const size_t NPQ1  = (size_t)BSZ * C_ * N_;    // 196608 floats (per chunk)
  const size_t NPART = (size_t)8 * BSZ * L_ * 128; // 1605632
  const size_t NWT   = (size_t)C_ * 128;         // 196608
  float* ws = (float*)d_ws;
  float* xb    = ws;                 // pre-conv x  (reused as delta later)
  float* zb    = xb + NBCL;
  float* xc    = zb + NBCL;          // post-conv x
  float* xdbl  = xc + NBCL;          // dt rows only: B*96*L
  float* BtArr = xdbl + NDT;
  float* CtArr = BtArr + NBT;
  float* Pbuf  = CtArr + NBT;        // big region: part+Wt, later P/Q
  float* delta = xb;                 // reuse: xb dead after conv

  size_t base_floats = 3 * NBCL + NDT + 2 * NBT;
  size_t avail = ws_size / 4 > base_floats ? ws_size / 4 - base_floats : 0;
  bool split_ok = avail >= NPART + NWT;

  // K1: in_proj GEMM  (M=12544 = 196*64, N=384 = 6*64)
  k_inproj<<<dim3(196, 6), 256, 0, stream>>>(hidden, in_proj_w, xb, zb);
  // K2: conv + silu
  k_conv<<<(int)(NBCL / 256), 256, 0, stream>>>(xb, conv_w, conv_b, xc);

  // K3: x_dbl GEMM (+ B/C transpose)
  if (split_ok) {
    float* part = Pbuf;
    float* Wt   = Pbuf + NPART;
    k_wtrans<<<(int)(NWT / 256), 256, 0, stream>>>(x_proj_w, Wt);
    k_xdblsplit<<<dim3(25, 8, BSZ), 256, 0, stream>>>(xc, Wt, part);
    k_xreduce<<<dim3(49, BSZ), 256, 0, stream>>>(part, xdbl, BtArr, CtArr);
  } else {
    k_xdbl_mono<<<dim3(4, 16, BSZ), 256, 0, stream>>>(xc, x_proj_w, xdbl, BtArr, CtArr);
  }

  // K4: delta GEMM + softplus (LDS-tiled; N = B*L = 1568 -> 25 tiles, M = 1536 -> 24 tiles)
  k_delta_gemm<<<dim3(25, 24), 256, 0, stream>>>(xdbl, dt_proj_w, dt_bias, delta);

  // K5: chunked scan, chunk count chosen by available workspace
  if (avail >= 2 * NPQ1 * 14) {
    float4* P4 = (float4*)Pbuf;
    float4* Q4 = (float4*)(Pbuf + NPQ1 * 14);
    int nthreads = (int)(BSZ * C_ * 14 * 4);   // 688128
    k_scan1<14, 14><<<nthreads / 256, 256, 0, stream>>>(delta, xc, BtArr, A_log, P4, Q4);
    k_scan2<14, 14><<<nthreads / 256, 256, 0, stream>>>(delta, xc, zb, BtArr, CtArr, A_log, D_param, P4, Q4, out);
  } else if (avail >= 2 * NPQ1 * 7) {
    float4* P4 = (float4*)Pbuf;
    float4* Q4 = (float4*)(Pbuf + NPQ1 * 7);
    int nthreads = (int)(BSZ * C_ * 7 * 4);    // 344064
    k_scan1<7, 28><<<nthreads / 256, 256, 0, stream>>>(delta, xc, BtArr, A_log, P4, Q4);
    k_scan2<7, 28><<<nthreads / 256, 256, 0, stream>>>(delta, xc, zb, BtArr, CtArr, A_log, D_param, P4, Q4, out);
  } else {
    float4* P4 = (float4*)Pbuf;
    float4* Q4 = (float4*)(Pbuf + NPQ1 * 2);
    int nthreads = (int)(BSZ * C_ * 2 * 4);    // 98304
    k_scan1<2, 98><<<nthreads / 256, 256, 0, stream>>>(delta, xc, BtArr, A_log, P4, Q4);
    k_scan2<2, 98><<<nthreads / 256, 256, 0, stream>>>(delta, xc, zb, BtArr, CtArr, A_log, D_param, P4, Q4, out);
  }
}

// Round 6
// 167.295 us; speedup vs baseline: 2.3668x; 1.0597x over previous
//
#include <hip/hip_runtime.h>
#include <hip/hip_bf16.h>
#include <cstddef>

// Problem constants
#define BSZ 8
#define T_  8
#define L_  196
#define D_  192
#define E_  192
#define C_  1536   // E*T
#define N_  16
#define K_  4
#define R_  96

// ---------------- Kernel 1: in_proj GEMM (128x128 tile, 8x8/thread) ----------------
// xz[b,e,t,l] = sum_d hidden[b,t,l,d] * W[e,d]
// M = B*T*L = 12544 = 98*128, N = 384 = 3*128, K = 192 = 12*16
__global__ __launch_bounds__(256) void k_inproj(
    const float* __restrict__ A,   // hidden, M x 192
    const float* __restrict__ W,   // 384 x 192
    float* __restrict__ xb, float* __restrict__ zb) {
  __shared__ float As[16][132];
  __shared__ float Bs[16][132];
  int tid = threadIdx.x;
  int m0 = blockIdx.x * 128;
  int n0 = blockIdx.y * 128;
  int tx = tid & 15, ty = tid >> 4;
  float acc[8][8] = {};
  for (int k0 = 0; k0 < 192; k0 += 16) {
#pragma unroll
    for (int i = 0; i < 2; i++) {
      int idx = tid + i * 256;          // 0..511
      int m = idx >> 2, k4 = (idx & 3) * 4;
      float4 v = *(const float4*)&A[(size_t)(m0 + m) * 192 + k0 + k4];
      As[k4 + 0][m] = v.x;
      As[k4 + 1][m] = v.y;
      As[k4 + 2][m] = v.z;
      As[k4 + 3][m] = v.w;
    }
#pragma unroll
    for (int i = 0; i < 2; i++) {
      int idx = tid + i * 256;
      int n = idx >> 2, k4 = (idx & 3) * 4;
      float4 v = *(const float4*)&W[(size_t)(n0 + n) * 192 + k0 + k4];
      Bs[k4 + 0][n] = v.x;
      Bs[k4 + 1][n] = v.y;
      Bs[k4 + 2][n] = v.z;
      Bs[k4 + 3][n] = v.w;
    }
    __syncthreads();
#pragma unroll
    for (int kk = 0; kk < 16; kk++) {
      float a_[8], b_[8];
      *(float4*)&a_[0] = *(const float4*)&As[kk][ty * 4];
      *(float4*)&a_[4] = *(const float4*)&As[kk][ty * 4 + 64];
      *(float4*)&b_[0] = *(const float4*)&Bs[kk][tx * 4];
      *(float4*)&b_[4] = *(const float4*)&Bs[kk][tx * 4 + 64];
#pragma unroll
      for (int i = 0; i < 8; i++)
#pragma unroll
        for (int j = 0; j < 8; j++) acc[i][j] += a_[i] * b_[j];
    }
    __syncthreads();
  }
#pragma unroll
  for (int i = 0; i < 8; i++) {
    int m = m0 + ty * 4 + (i & 3) + ((i >> 2) * 64);
    int b = m / (T_ * L_);
    int r = m % (T_ * L_);
    int t = r / L_;
    int l = r % L_;
#pragma unroll
    for (int j = 0; j < 8; j++) {
      int e = n0 + tx * 4 + (j & 3) + ((j >> 2) * 64);
      float v = acc[i][j];
      if (e < E_) {
        int c = e * T_ + t;
        xb[((size_t)b * C_ + c) * L_ + l] = v;
      } else {
        int c = (e - E_) * T_ + t;
        zb[((size_t)b * C_ + c) * L_ + l] = v;
      }
    }
  }
}

// ---------------- Kernel 2: depthwise causal conv (K=4) + bias + SiLU ----------------
__global__ __launch_bounds__(256) void k_conv(
    const float* __restrict__ xb, const float* __restrict__ conv_w,
    const float* __restrict__ conv_b, float* __restrict__ xc) {
  int idx = blockIdx.x * 256 + threadIdx.x;   // B*C*L = 2408448 exactly
  int l = idx % L_;
  int bc = idx / L_;
  int c = bc % C_;
  const float* xrow = xb + (size_t)bc * L_;
  const float* w = conv_w + c * K_;
  float acc = conv_b[c];
#pragma unroll
  for (int k = 0; k < K_; k++) {
    int ll = l - (K_ - 1) + k;
    if (ll >= 0) acc += xrow[ll] * w[k];
  }
  xc[idx] = acc / (1.f + __expf(-acc));
}

// ---------------- Kernel 3a: W transpose (128x1536 -> [c][128]) ----------------
__global__ __launch_bounds__(256) void k_wtrans(
    const float* __restrict__ W, float* __restrict__ Wt) {
  int idx = blockIdx.x * 256 + threadIdx.x;  // 128*1536 = 196608
  int r = idx / 1536;
  int c = idx - r * 1536;
  Wt[(size_t)c * 128 + r] = W[idx];
}

// ---------------- Kernel 3b: LDS-tiled split-K x_dbl GEMM ----------------
// part[kc][b][l][128] = sum_{c in chunk kc (96 wide)} xc[b][c][l] * Wt[c][r]
// block: 128 r x 64 flattened (b,l) cols; grid (25 col-tiles, 16 kc)
#define XKK 32
__global__ __launch_bounds__(256) void k_xdbl_tile(
    const float* __restrict__ xc, const float* __restrict__ Wt,
    float* __restrict__ part) {
  __shared__ float Ws2[XKK][128];
  __shared__ float Xs[XKK][64];
  int tid = threadIdx.x;
  int n0 = blockIdx.x * 64;     // flattened (b,l) in [0,1568)
  int c0 = blockIdx.y * 96;     // K-chunk
  int tx = tid & 15, ty = tid >> 4;
  float acc[8][4] = {};
  for (int ck = 0; ck < 96; ck += XKK) {
#pragma unroll
    for (int i = 0; i < 4; i++) {
      int idx = tid + i * 256;        // 0..1023
      int c = idx >> 5, r4 = (idx & 31) * 4;
      *(float4*)&Ws2[c][r4] = *(const float4*)&Wt[(size_t)(c0 + ck + c) * 128 + r4];
    }
#pragma unroll
    for (int i = 0; i < 8; i++) {
      int idx = tid + i * 256;        // 0..2047
      int c = idx >> 6, j = idx & 63;
      int n = n0 + j;
      float v = 0.f;
      if (n < BSZ * L_) {
        int b = n / L_, l = n - b * L_;
        v = xc[((size_t)b * C_ + c0 + ck + c) * L_ + l];
      }
      Xs[c][j] = v;
    }
    __syncthreads();
#pragma unroll
    for (int kk = 0; kk < XKK; kk++) {
      float w_[8], x_[4];
      *(float4*)&w_[0] = *(const float4*)&Ws2[kk][ty * 8];
      *(float4*)&w_[4] = *(const float4*)&Ws2[kk][ty * 8 + 4];
      *(float4*)&x_[0] = *(const float4*)&Xs[kk][tx * 4];
#pragma unroll
      for (int i = 0; i < 8; i++)
#pragma unroll
        for (int j = 0; j < 4; j++) acc[i][j] += w_[i] * x_[j];
    }
    __syncthreads();
  }
  int kc = blockIdx.y;
#pragma unroll
  for (int j = 0; j < 4; j++) {
    int n = n0 + tx * 4 + j;
    if (n < BSZ * L_) {
      int b = n / L_, l = n - b * L_;
      float* pp = &part[(((size_t)kc * 8 + b) * L_ + l) * 128 + ty * 8];
      float4 v0 = {acc[0][j], acc[1][j], acc[2][j], acc[3][j]};
      float4 v1 = {acc[4][j], acc[5][j], acc[6][j], acc[7][j]};
      *(float4*)&pp[0] = v0;
      *(float4*)&pp[4] = v1;
    }
  }
}

// ---------------- Kernel 3c: reduce partials -> dt [b][96][l], Bt/Ct [b][l][16] ----------------
__global__ __launch_bounds__(256) void k_xreduce(
    const float* __restrict__ part, float* __restrict__ xdbl,
    float* __restrict__ Bt, float* __restrict__ Ct) {
  int tx = threadIdx.x & 63;
  int ty = threadIdx.x >> 6;
  int l = blockIdx.x * 4 + ty;      // 49*4 = 196 exactly
  int b = blockIdx.y;
  size_t o = ((size_t)b * L_ + l) * 128 + tx;
  float v0 = 0.f, v1 = 0.f;
#pragma unroll
  for (int kc = 0; kc < 16; kc++) {
    v0 += part[(size_t)kc * (8 * L_ * 128) + o];
    v1 += part[(size_t)kc * (8 * L_ * 128) + o + 64];
  }
  int r1 = tx + 64;
  xdbl[((size_t)b * 96 + tx) * L_ + l] = v0;
  if (r1 < 96) {
    xdbl[((size_t)b * 96 + r1) * L_ + l] = v1;
  } else if (r1 < 96 + N_) {
    Bt[((size_t)b * L_ + l) * N_ + (r1 - 96)] = v1;
  } else {
    Ct[((size_t)b * L_ + l) * N_ + (r1 - 96 - N_)] = v1;
  }
}

// ---------------- Kernel 3-mono (fallback, small ws): x_dbl GEMM ----------------
__global__ __launch_bounds__(256) void k_xdbl_mono(
    const float* __restrict__ xc, const float* __restrict__ W,  // 128 x 1536
    float* __restrict__ xdbl, float* __restrict__ Bt, float* __restrict__ Ct) {
  int tx = threadIdx.x & 63;
  int ty = threadIdx.x >> 6;
  int l = blockIdx.x * 64 + tx;
  int r0 = blockIdx.y * 4 + ty;
  int r1 = r0 + 64;
  int b = blockIdx.z;
  if (l >= L_) return;
  const float* xcb = xc + (size_t)b * C_ * L_;
  float acc0 = 0.f, acc1 = 0.f;
#pragma unroll 4
  for (int c = 0; c < C_; c++) {
    float v = xcb[(size_t)c * L_ + l];
    acc0 += v * W[(size_t)r0 * C_ + c];
    acc1 += v * W[(size_t)r1 * C_ + c];
  }
  xdbl[((size_t)b * 96 + r0) * L_ + l] = acc0;
  if (r1 < 96) {
    xdbl[((size_t)b * 96 + r1) * L_ + l] = acc1;
  } else if (r1 < 96 + N_) {
    Bt[((size_t)b * L_ + l) * N_ + (r1 - 96)] = acc1;
  } else {
    Ct[((size_t)b * L_ + l) * N_ + (r1 - 96 - N_)] = acc1;
  }
}

// ---------------- Kernel 4: delta GEMM + softplus (LDS-tiled) ----------------
__global__ __launch_bounds__(256) void k_delta_gemm(
    const float* __restrict__ dtm, const float* __restrict__ Wdt,  // 1536 x 96
    const float* __restrict__ dt_bias, float* __restrict__ delta) {
  __shared__ float Ws[96][68];   // Ws[r][i] = Wdt[c0+i][r]
  __shared__ float Ds[96][68];   // Ds[r][j] = dtm[b][r][l], n0+j=(b,l)
  int tid = threadIdx.x;
  int n0 = blockIdx.x * 64;      // flattened (b,l), 25 tiles over 1568
  int c0 = blockIdx.y * 64;
  for (int idx = tid; idx < 64 * 96; idx += 256) {
    int i = idx / 96, r = idx - i * 96;
    Ws[r][i] = Wdt[(size_t)(c0 + i) * 96 + r];
  }
  for (int idx = tid; idx < 96 * 64; idx += 256) {
    int r = idx >> 6, j = idx & 63;
    int n = n0 + j;
    float v = 0.f;
    if (n < BSZ * L_) {
      int b = n / L_, l = n - b * L_;
      v = dtm[((size_t)b * 96 + r) * L_ + l];
    }
    Ds[r][j] = v;
  }
  __syncthreads();
  int tx = tid & 15, ty = tid >> 4;
  float acc[4][4] = {};
#pragma unroll 8
  for (int r = 0; r < 96; r++) {
    float4 av = *(const float4*)&Ws[r][ty * 4];
    float4 bv = *(const float4*)&Ds[r][tx * 4];
    float a_[4] = {av.x, av.y, av.z, av.w};
    float b_[4] = {bv.x, bv.y, bv.z, bv.w};
#pragma unroll
    for (int i = 0; i < 4; i++)
#pragma unroll
      for (int j = 0; j < 4; j++) acc[i][j] += a_[i] * b_[j];
  }
#pragma unroll
  for (int i = 0; i < 4; i++) {
    int c = c0 + ty * 4 + i;
    float bias = dt_bias[c];
#pragma unroll
    for (int j = 0; j < 4; j++) {
      int n = n0 + tx * 4 + j;
      if (n < BSZ * L_) {
        int b = n / L_, l = n - b * L_;
        float v = acc[i][j] + bias;
        float sp = (v > 20.f) ? v : __logf(1.f + __expf(v));
        delta[((size_t)b * C_ + c) * L_ + l] = sp;
      }
    }
  }
}

// ---------------- Kernel 5a: chunked scan pass 1 ----------------
template <int CH, int CL>
__global__ __launch_bounds__(256) void k_scan1(
    const float* __restrict__ delta, const float* __restrict__ xc,
    const float* __restrict__ Bt, const float* __restrict__ A_log,
    float4* __restrict__ P, float4* __restrict__ Q) {
  int idx = blockIdx.x * 256 + threadIdx.x;   // B*C*CH*4
  int nl = idx & 3;
  int pc = idx >> 2;
  int chunk = pc % CH;
  int bc = pc / CH;
  int b = bc / C_;
  int c = bc % C_;
  float4 a;
  a.x = -__expf(A_log[c * N_ + nl * 4 + 0]);
  a.y = -__expf(A_log[c * N_ + nl * 4 + 1]);
  a.z = -__expf(A_log[c * N_ + nl * 4 + 2]);
  a.w = -__expf(A_log[c * N_ + nl * 4 + 3]);
  const float* dp = delta + (size_t)bc * L_ + chunk * CL;
  const float* xp = xc + (size_t)bc * L_ + chunk * CL;
  const float* Btp = Bt + ((size_t)b * L_ + chunk * CL) * N_ + nl * 4;
  float4 h = {0.f, 0.f, 0.f, 0.f};
  float4 p = {1.f, 1.f, 1.f, 1.f};
#pragma unroll
  for (int l = 0; l < CL; l++) {
    float d = dp[l];
    float du = d * xp[l];
    float4 Bv = *(const float4*)(Btp + (size_t)l * N_);
    float ex, ey, ez, ew;
    ex = __expf(d * a.x); ey = __expf(d * a.y);
    ez = __expf(d * a.z); ew = __expf(d * a.w);
    h.x = h.x * ex + du * Bv.x; p.x *= ex;
    h.y = h.y * ey + du * Bv.y; p.y *= ey;
    h.z = h.z * ez + du * Bv.z; p.z *= ez;
    h.w = h.w * ew + du * Bv.w; p.w *= ew;
  }
  P[idx] = p;
  Q[idx] = h;
}

// ---------------- Kernel 5b: carry combine + chunk re-scan + output ----------------
template <int CH, int CL>
__global__ __launch_bounds__(256) void k_scan2(
    const float* __restrict__ delta, const float* __restrict__ xc,
    const float* __restrict__ zb, const float* __restrict__ Bt,
    const float* __restrict__ Ct, const float* __restrict__ A_log,
    const float* __restrict__ D_param,
    const float4* __restrict__ P, const float4* __restrict__ Q,
    float* __restrict__ out) {
  int idx = blockIdx.x * 256 + threadIdx.x;   // B*C*CH*4
  int nl = idx & 3;
  int pc = idx >> 2;
  int chunk = pc % CH;
  int bc = pc / CH;
  int b = bc / C_;
  int c = bc % C_;
  float4 a;
  a.x = -__expf(A_log[c * N_ + nl * 4 + 0]);
  a.y = -__expf(A_log[c * N_ + nl * 4 + 1]);
  a.z = -__expf(A_log[c * N_ + nl * 4 + 2]);
  a.w = -__expf(A_log[c * N_ + nl * 4 + 3]);
  float Dp = D_param[c];
  float4 h = {0.f, 0.f, 0.f, 0.f};
  size_t base = (size_t)bc * CH * 4 + nl;
  for (int k = 0; k < chunk; k++) {
    float4 pk = P[base + (size_t)k * 4];
    float4 qk = Q[base + (size_t)k * 4];
    h.x = pk.x * h.x + qk.x;
    h.y = pk.y * h.y + qk.y;
    h.z = pk.z * h.z + qk.z;
    h.w = pk.w * h.w + qk.w;
  }
  const int l0 = chunk * CL;
  const float* dp = delta + (size_t)bc * L_ + l0;
  const float* xp = xc + (size_t)bc * L_ + l0;
  const float* zp = zb + (size_t)bc * L_ + l0;
  const float* Btp = Bt + ((size_t)b * L_ + l0) * N_ + nl * 4;
  const float* Ctp = Ct + ((size_t)b * L_ + l0) * N_ + nl * 4;
  float* op = out + (size_t)bc * L_ + l0;
#pragma unroll
  for (int l = 0; l < CL; l++) {
    float d = dp[l];
    float xv = xp[l];
    float du = d * xv;
    float4 Bv = *(const float4*)(Btp + (size_t)l * N_);
    float4 Cv = *(const float4*)(Ctp + (size_t)l * N_);
    float ex, ey, ez, ew;
    ex = __expf(d * a.x); ey = __expf(d * a.y);
    ez = __expf(d * a.z); ew = __expf(d * a.w);
    h.x = h.x * ex + du * Bv.x;
    h.y = h.y * ey + du * Bv.y;
    h.z = h.z * ez + du * Bv.z;
    h.w = h.w * ew + du * Bv.w;
    float yv = h.x * Cv.x + h.y * Cv.y + h.z * Cv.z + h.w * Cv.w;
    yv += __shfl_xor(yv, 1);
    yv += __shfl_xor(yv, 2);
    if (nl == 0) {
      float zv = zp[l];
      float sz = zv / (1.f + __expf(-zv));
      op[l] = (yv + xv * Dp) * sz;
    }
  }
}

extern "C" void kernel_launch(void* const* d_in, const int* in_sizes, int n_in,
                              void* d_out, int out_size, void* d_ws, size_t ws_size,
                              hipStream_t stream) {
  const float* hidden    = (const float*)d_in[0];
  const float* in_proj_w = (const float*)d_in[1];
  const float* conv_w    = (const float*)d_in[2];
  const float* conv_b    = (const float*)d_in[3];
  const float* x_proj_w  = (const float*)d_in[4];
  const float* dt_proj_w = (const float*)d_in[5];
  const float* dt_bias   = (const float*)d_in[6];
  const float* A_log     = (const float*)d_in[7];
  const float* D_param   = (const float*)d_in[8];
  float* out = (float*)d_out;

  const size_t NBCL  = (size_t)BSZ * C_ * L_;    // 2408448
  const size_t NDT   = (size_t)BSZ * 96 * L_;    // 150528
  const size_t NBT   = (size_t)BSZ * L_ * N_;    // 25088
  const size_t NPQ1  = (size_t)BSZ * C_ * N_;    // 196608 floats (per chunk)
  const size_t NPART = (size_t)16 * BSZ * L_ * 128; // 3211264
  const size_t NWT   = (size_t)C_ * 128;         // 196608
  float* ws = (float*)d_ws;
  float* xb    = ws;                 // pre-conv x  (reused as delta later)
  float* zb    = xb + NBCL;
  float* xc    = zb + NBCL;          // post-conv x
  float* xdbl  = xc + NBCL;          // dt rows only: B*96*L
  float* BtArr = xdbl + NDT;
  float* CtArr = BtArr + NBT;
  float* Pbuf  = CtArr + NBT;        // big region: part+Wt, later P/Q
  float* delta = xb;                 // reuse: xb dead after conv

  size_t base_floats = 3 * NBCL + NDT + 2 * NBT;
  size_t avail = ws_size / 4 > base_floats ? ws_size / 4 - base_floats : 0;
  bool split_ok = avail >= NPART + NWT;

  // K1: in_proj GEMM
  k_inproj<<<dim3(98, 3), 256, 0, stream>>>(hidden, in_proj_w, xb, zb);
  // K2: conv + silu
  k_conv<<<(int)(NBCL / 256), 256, 0, stream>>>(xb, conv_w, conv_b, xc);

  // K3: x_dbl GEMM (+ B/C transpose)
  if (split_ok) {
    float* part = Pbuf;
    float* Wt   = Pbuf + NPART;
    k_wtrans<<<(int)(NWT / 256), 256, 0, stream>>>(x_proj_w, Wt);
    k_xdbl_tile<<<dim3(25, 16), 256, 0, stream>>>(xc, Wt, part);
    k_xreduce<<<dim3(49, BSZ), 256, 0, stream>>>(part, xdbl, BtArr, CtArr);
  } else {
    k_xdbl_mono<<<dim3(4, 16, BSZ), 256, 0, stream>>>(xc, x_proj_w, xdbl, BtArr, CtArr);
  }

  // K4: delta GEMM + softplus (N = B*L = 1568 -> 25 tiles, M = 1536 -> 24 tiles)
  k_delta_gemm<<<dim3(25, 24), 256, 0, stream>>>(xdbl, dt_proj_w, dt_bias, delta);

  // K5: chunked scan, chunk count chosen by available workspace
  if (avail >= 2 * NPQ1 * 14) {
    float4* P4 = (float4*)Pbuf;
    float4* Q4 = (float4*)(Pbuf + NPQ1 * 14);
    int nthreads = (int)(BSZ * C_ * 14 * 4);   // 688128
    k_scan1<14, 14><<<nthreads / 256, 256, 0, stream>>>(delta, xc, BtArr, A_log, P4, Q4);
    k_scan2<14, 14><<<nthreads / 256, 256, 0, stream>>>(delta, xc, zb, BtArr, CtArr, A_log, D_param, P4, Q4, out);
  } else if (avail >= 2 * NPQ1 * 7) {
    float4* P4 = (float4*)Pbuf;
    float4* Q4 = (float4*)(Pbuf + NPQ1 * 7);
    int nthreads = (int)(BSZ * C_ * 7 * 4);    // 344064
    k_scan1<7, 28><<<nthreads / 256, 256, 0, stream>>>(delta, xc, BtArr, A_log, P4, Q4);
    k_scan2<7, 28><<<nthreads / 256, 256, 0, stream>>>(delta, xc, zb, BtArr, CtArr, A_log, D_param, P4, Q4, out);
  } else {
    float4* P4 = (float4*)Pbuf;
    float4* Q4 = (float4*)(Pbuf + NPQ1 * 2);
    int nthreads = (int)(BSZ * C_ * 2 * 4);    // 98304
    k_scan1<2, 98><<<nthreads / 256, 256, 0, stream>>>(delta, xc, BtArr, A_log, P4, Q4);
    k_scan2<2, 98><<<nthreads / 256, 256, 0, stream>>>(delta, xc, zb, BtArr, CtArr, A_log, D_param, P4, Q4, out);
  }
}

// Round 7
// 145.408 us; speedup vs baseline: 2.7231x; 1.1505x over previous
//
#include <hip/hip_runtime.h>
#include <hip/hip_bf16.h>
#include <cstddef>

// Problem constants
#define BSZ 8
#define T_  8
#define L_  196
#define D_  192
#define E_  192
#define C_  1536   // E*T
#define N_  16
#define K_  4
#define R_  96

typedef __attribute__((ext_vector_type(8))) short short8;
typedef __attribute__((ext_vector_type(4))) float f32x4;
typedef unsigned short ushort_t;

// ---------------- Kernel 0: fp32 -> bf16 cast (RNE), 8 elems/thread ----------------
__global__ __launch_bounds__(256) void k_cast_bf16(
    const float* __restrict__ in, ushort_t* __restrict__ out, int n8) {
  int i = blockIdx.x * 256 + threadIdx.x;
  if (i >= n8) return;
  const float4* ip = (const float4*)in;
  float4 v0 = ip[(size_t)i * 2];
  float4 v1 = ip[(size_t)i * 2 + 1];
  union { ushort_t u[8]; uint4 v; } r;
  float f[8] = {v0.x, v0.y, v0.z, v0.w, v1.x, v1.y, v1.z, v1.w};
#pragma unroll
  for (int k = 0; k < 8; k++) {
    unsigned int bits = __float_as_uint(f[k]);
    bits += 0x7FFFu + ((bits >> 16) & 1u);   // RNE
    r.u[k] = (ushort_t)(bits >> 16);
  }
  ((uint4*)out)[i] = r.v;
}

// ---------------- Kernel 1: in_proj GEMM via MFMA (bf16) ----------------
// D[m][e] = sum_d hidden[m][d] * W[e][d];  A=[12544][192], B^T=W=[384][192]
// grid (196, 4): 64 rows x 96 cols per block; 4 waves, wave w = rows m0+w*16.
__global__ __launch_bounds__(256) void k_inproj_mfma(
    const ushort_t* __restrict__ hb, const ushort_t* __restrict__ wb,
    float* __restrict__ xb, float* __restrict__ zb) {
  __shared__ float smem[64][97];
  int tid = threadIdx.x;
  int wave = tid >> 6, lane = tid & 63;
  int m0b = blockIdx.x * 64;
  int n0 = blockIdx.y * 96;
  int row = lane & 15, kg = lane >> 4;
  int m0w = m0b + wave * 16;

  f32x4 acc[6] = {};
  const ushort_t* ap = hb + (size_t)(m0w + row) * 192 + kg * 8;
#pragma unroll
  for (int ks = 0; ks < 6; ks++) {
    short8 a = *(const short8*)(ap + ks * 32);
#pragma unroll
    for (int nt = 0; nt < 6; nt++) {
      short8 b = *(const short8*)(wb + (size_t)(n0 + nt * 16 + row) * 192 + ks * 32 + kg * 8);
      acc[nt] = __builtin_amdgcn_mfma_f32_16x16x32_bf16(a, b, acc[nt], 0, 0, 0);
    }
  }
  // stage to LDS: D row = kg*4+j (M), col = lane&15 (N)
#pragma unroll
  for (int nt = 0; nt < 6; nt++) {
#pragma unroll
    for (int j = 0; j < 4; j++) {
      smem[wave * 16 + kg * 4 + j][nt * 16 + row] = acc[nt][j];
    }
  }
  __syncthreads();
  // cooperative transposed store: fixed e -> contiguous m
  int mloc = tid & 63, eof = tid >> 6;
  int m_glob = m0b + mloc;
  int b = m_glob / 1568, u = m_glob % 1568;
  size_t obase = (size_t)b * 301056 + u;   // b*C*L + u
#pragma unroll
  for (int e = eof; e < 96; e += 4) {
    int eg = n0 + e;
    float v = smem[mloc][e];
    if (eg < 192) xb[obase + (size_t)eg * 1568] = v;
    else          zb[obase + (size_t)(eg - 192) * 1568] = v;
  }
}

// ---------------- Kernel 1-fallback: fp32 in_proj (128x128 tile) ----------------
__global__ __launch_bounds__(256) void k_inproj_f32(
    const float* __restrict__ A, const float* __restrict__ W,
    float* __restrict__ xb, float* __restrict__ zb) {
  __shared__ float As[16][132];
  __shared__ float Bs[16][132];
  int tid = threadIdx.x;
  int m0 = blockIdx.x * 128;
  int n0 = blockIdx.y * 128;
  int tx = tid & 15, ty = tid >> 4;
  float acc[8][8] = {};
  for (int k0 = 0; k0 < 192; k0 += 16) {
#pragma unroll
    for (int i = 0; i < 2; i++) {
      int idx = tid + i * 256;
      int m = idx >> 2, k4 = (idx & 3) * 4;
      float4 v = *(const float4*)&A[(size_t)(m0 + m) * 192 + k0 + k4];
      As[k4 + 0][m] = v.x; As[k4 + 1][m] = v.y;
      As[k4 + 2][m] = v.z; As[k4 + 3][m] = v.w;
    }
#pragma unroll
    for (int i = 0; i < 2; i++) {
      int idx = tid + i * 256;
      int n = idx >> 2, k4 = (idx & 3) * 4;
      float4 v = *(const float4*)&W[(size_t)(n0 + n) * 192 + k0 + k4];
      Bs[k4 + 0][n] = v.x; Bs[k4 + 1][n] = v.y;
      Bs[k4 + 2][n] = v.z; Bs[k4 + 3][n] = v.w;
    }
    __syncthreads();
#pragma unroll
    for (int kk = 0; kk < 16; kk++) {
      float a_[8], b_[8];
      *(float4*)&a_[0] = *(const float4*)&As[kk][ty * 4];
      *(float4*)&a_[4] = *(const float4*)&As[kk][ty * 4 + 64];
      *(float4*)&b_[0] = *(const float4*)&Bs[kk][tx * 4];
      *(float4*)&b_[4] = *(const float4*)&Bs[kk][tx * 4 + 64];
#pragma unroll
      for (int i = 0; i < 8; i++)
#pragma unroll
        for (int j = 0; j < 8; j++) acc[i][j] += a_[i] * b_[j];
    }
    __syncthreads();
  }
#pragma unroll
  for (int i = 0; i < 8; i++) {
    int m = m0 + ty * 4 + (i & 3) + ((i >> 2) * 64);
    int b = m / (T_ * L_);
    int r = m % (T_ * L_);
    int t = r / L_;
    int l = r % L_;
#pragma unroll
    for (int j = 0; j < 8; j++) {
      int e = n0 + tx * 4 + (j & 3) + ((j >> 2) * 64);
      float v = acc[i][j];
      if (e < E_) {
        int c = e * T_ + t;
        xb[((size_t)b * C_ + c) * L_ + l] = v;
      } else {
        int c = (e - E_) * T_ + t;
        zb[((size_t)b * C_ + c) * L_ + l] = v;
      }
    }
  }
}

// ---------------- Kernel 2: depthwise causal conv (K=4) + bias + SiLU ----------------
__global__ __launch_bounds__(256) void k_conv(
    const float* __restrict__ xb, const float* __restrict__ conv_w,
    const float* __restrict__ conv_b, float* __restrict__ xc) {
  int idx = blockIdx.x * 256 + threadIdx.x;   // B*C*L = 2408448 exactly
  int l = idx % L_;
  int bc = idx / L_;
  int c = bc % C_;
  const float* xrow = xb + (size_t)bc * L_;
  const float* w = conv_w + c * K_;
  float acc = conv_b[c];
#pragma unroll
  for (int k = 0; k < K_; k++) {
    int ll = l - (K_ - 1) + k;
    if (ll >= 0) acc += xrow[ll] * w[k];
  }
  xc[idx] = acc / (1.f + __expf(-acc));
}

// ---------------- Kernel 3a: W transpose (128x1536 -> [c][128]) ----------------
__global__ __launch_bounds__(256) void k_wtrans(
    const float* __restrict__ W, float* __restrict__ Wt) {
  int idx = blockIdx.x * 256 + threadIdx.x;  // 128*1536 = 196608
  int r = idx / 1536;
  int c = idx - r * 1536;
  Wt[(size_t)c * 128 + r] = W[idx];
}

// ---------------- Kernel 3b: LDS-tiled split-K x_dbl GEMM ----------------
#define XKK 32
__global__ __launch_bounds__(256) void k_xdbl_tile(
    const float* __restrict__ xc, const float* __restrict__ Wt,
    float* __restrict__ part) {
  __shared__ float Ws2[XKK][128];
  __shared__ float Xs[XKK][64];
  int tid = threadIdx.x;
  int n0 = blockIdx.x * 64;     // flattened (b,l) in [0,1568)
  int c0 = blockIdx.y * 96;     // K-chunk
  int tx = tid & 15, ty = tid >> 4;
  float acc[8][4] = {};
  for (int ck = 0; ck < 96; ck += XKK) {
#pragma unroll
    for (int i = 0; i < 4; i++) {
      int idx = tid + i * 256;
      int c = idx >> 5, r4 = (idx & 31) * 4;
      *(float4*)&Ws2[c][r4] = *(const float4*)&Wt[(size_t)(c0 + ck + c) * 128 + r4];
    }
#pragma unroll
    for (int i = 0; i < 8; i++) {
      int idx = tid + i * 256;
      int c = idx >> 6, j = idx & 63;
      int n = n0 + j;
      float v = 0.f;
      if (n < BSZ * L_) {
        int b = n / L_, l = n - b * L_;
        v = xc[((size_t)b * C_ + c0 + ck + c) * L_ + l];
      }
      Xs[c][j] = v;
    }
    __syncthreads();
#pragma unroll
    for (int kk = 0; kk < XKK; kk++) {
      float w_[8], x_[4];
      *(float4*)&w_[0] = *(const float4*)&Ws2[kk][ty * 8];
      *(float4*)&w_[4] = *(const float4*)&Ws2[kk][ty * 8 + 4];
      *(float4*)&x_[0] = *(const float4*)&Xs[kk][tx * 4];
#pragma unroll
      for (int i = 0; i < 8; i++)
#pragma unroll
        for (int j = 0; j < 4; j++) acc[i][j] += w_[i] * x_[j];
    }
    __syncthreads();
  }
  int kc = blockIdx.y;
#pragma unroll
  for (int j = 0; j < 4; j++) {
    int n = n0 + tx * 4 + j;
    if (n < BSZ * L_) {
      int b = n / L_, l = n - b * L_;
      float* pp = &part[(((size_t)kc * 8 + b) * L_ + l) * 128 + ty * 8];
      float4 v0 = {acc[0][j], acc[1][j], acc[2][j], acc[3][j]};
      float4 v1 = {acc[4][j], acc[5][j], acc[6][j], acc[7][j]};
      *(float4*)&pp[0] = v0;
      *(float4*)&pp[4] = v1;
    }
  }
}

// ---------------- Kernel 3c: reduce partials -> dt [b][96][l], Bt/Ct [b][l][16] ----------------
__global__ __launch_bounds__(256) void k_xreduce(
    const float* __restrict__ part, float* __restrict__ xdbl,
    float* __restrict__ Bt, float* __restrict__ Ct) {
  int tx = threadIdx.x & 63;
  int ty = threadIdx.x >> 6;
  int l = blockIdx.x * 4 + ty;      // 49*4 = 196 exactly
  int b = blockIdx.y;
  size_t o = ((size_t)b * L_ + l) * 128 + tx;
  float v0 = 0.f, v1 = 0.f;
#pragma unroll
  for (int kc = 0; kc < 16; kc++) {
    v0 += part[(size_t)kc * (8 * L_ * 128) + o];
    v1 += part[(size_t)kc * (8 * L_ * 128) + o + 64];
  }
  int r1 = tx + 64;
  xdbl[((size_t)b * 96 + tx) * L_ + l] = v0;
  if (r1 < 96) {
    xdbl[((size_t)b * 96 + r1) * L_ + l] = v1;
  } else if (r1 < 96 + N_) {
    Bt[((size_t)b * L_ + l) * N_ + (r1 - 96)] = v1;
  } else {
    Ct[((size_t)b * L_ + l) * N_ + (r1 - 96 - N_)] = v1;
  }
}

// ---------------- Kernel 3-mono (fallback, small ws): x_dbl GEMM ----------------
__global__ __launch_bounds__(256) void k_xdbl_mono(
    const float* __restrict__ xc, const float* __restrict__ W,  // 128 x 1536
    float* __restrict__ xdbl, float* __restrict__ Bt, float* __restrict__ Ct) {
  int tx = threadIdx.x & 63;
  int ty = threadIdx.x >> 6;
  int l = blockIdx.x * 64 + tx;
  int r0 = blockIdx.y * 4 + ty;
  int r1 = r0 + 64;
  int b = blockIdx.z;
  if (l >= L_) return;
  const float* xcb = xc + (size_t)b * C_ * L_;
  float acc0 = 0.f, acc1 = 0.f;
#pragma unroll 4
  for (int c = 0; c < C_; c++) {
    float v = xcb[(size_t)c * L_ + l];
    acc0 += v * W[(size_t)r0 * C_ + c];
    acc1 += v * W[(size_t)r1 * C_ + c];
  }
  xdbl[((size_t)b * 96 + r0) * L_ + l] = acc0;
  if (r1 < 96) {
    xdbl[((size_t)b * 96 + r1) * L_ + l] = acc1;
  } else if (r1 < 96 + N_) {
    Bt[((size_t)b * L_ + l) * N_ + (r1 - 96)] = acc1;
  } else {
    Ct[((size_t)b * L_ + l) * N_ + (r1 - 96 - N_)] = acc1;
  }
}

// ---------------- Kernel 4: delta GEMM + softplus (LDS-tiled) ----------------
__global__ __launch_bounds__(256) void k_delta_gemm(
    const float* __restrict__ dtm, const float* __restrict__ Wdt,  // 1536 x 96
    const float* __restrict__ dt_bias, float* __restrict__ delta) {
  __shared__ float Ws[96][68];
  __shared__ float Ds[96][68];
  int tid = threadIdx.x;
  int n0 = blockIdx.x * 64;
  int c0 = blockIdx.y * 64;
  for (int idx = tid; idx < 64 * 96; idx += 256) {
    int i = idx / 96, r = idx - i * 96;
    Ws[r][i] = Wdt[(size_t)(c0 + i) * 96 + r];
  }
  for (int idx = tid; idx < 96 * 64; idx += 256) {
    int r = idx >> 6, j = idx & 63;
    int n = n0 + j;
    float v = 0.f;
    if (n < BSZ * L_) {
      int b = n / L_, l = n - b * L_;
      v = dtm[((size_t)b * 96 + r) * L_ + l];
    }
    Ds[r][j] = v;
  }
  __syncthreads();
  int tx = tid & 15, ty = tid >> 4;
  float acc[4][4] = {};
#pragma unroll 8
  for (int r = 0; r < 96; r++) {
    float4 av = *(const float4*)&Ws[r][ty * 4];
    float4 bv = *(const float4*)&Ds[r][tx * 4];
    float a_[4] = {av.x, av.y, av.z, av.w};
    float b_[4] = {bv.x, bv.y, bv.z, bv.w};
#pragma unroll
    for (int i = 0; i < 4; i++)
#pragma unroll
      for (int j = 0; j < 4; j++) acc[i][j] += a_[i] * b_[j];
  }
#pragma unroll
  for (int i = 0; i < 4; i++) {
    int c = c0 + ty * 4 + i;
    float bias = dt_bias[c];
#pragma unroll
    for (int j = 0; j < 4; j++) {
      int n = n0 + tx * 4 + j;
      if (n < BSZ * L_) {
        int b = n / L_, l = n - b * L_;
        float v = acc[i][j] + bias;
        float sp = (v > 20.f) ? v : __logf(1.f + __expf(v));
        delta[((size_t)b * C_ + c) * L_ + l] = sp;
      }
    }
  }
}

// ---------------- Kernel 5a: chunked scan pass 1 ----------------
template <int CH, int CL>
__global__ __launch_bounds__(256) void k_scan1(
    const float* __restrict__ delta, const float* __restrict__ xc,
    const float* __restrict__ Bt, const float* __restrict__ A_log,
    float4* __restrict__ P, float4* __restrict__ Q) {
  int idx = blockIdx.x * 256 + threadIdx.x;   // B*C*CH*4
  int nl = idx & 3;
  int pc = idx >> 2;
  int chunk = pc % CH;
  int bc = pc / CH;
  int b = bc / C_;
  int c = bc % C_;
  float4 a;
  a.x = -__expf(A_log[c * N_ + nl * 4 + 0]);
  a.y = -__expf(A_log[c * N_ + nl * 4 + 1]);
  a.z = -__expf(A_log[c * N_ + nl * 4 + 2]);
  a.w = -__expf(A_log[c * N_ + nl * 4 + 3]);
  const float* dp = delta + (size_t)bc * L_ + chunk * CL;
  const float* xp = xc + (size_t)bc * L_ + chunk * CL;
  const float* Btp = Bt + ((size_t)b * L_ + chunk * CL) * N_ + nl * 4;
  float4 h = {0.f, 0.f, 0.f, 0.f};
  float4 p = {1.f, 1.f, 1.f, 1.f};
#pragma unroll
  for (int l = 0; l < CL; l++) {
    float d = dp[l];
    float du = d * xp[l];
    float4 Bv = *(const float4*)(Btp + (size_t)l * N_);
    float ex, ey, ez, ew;
    ex = __expf(d * a.x); ey = __expf(d * a.y);
    ez = __expf(d * a.z); ew = __expf(d * a.w);
    h.x = h.x * ex + du * Bv.x; p.x *= ex;
    h.y = h.y * ey + du * Bv.y; p.y *= ey;
    h.z = h.z * ez + du * Bv.z; p.z *= ez;
    h.w = h.w * ew + du * Bv.w; p.w *= ew;
  }
  P[idx] = p;
  Q[idx] = h;
}

// ---------------- Kernel 5b: carry combine + chunk re-scan + output ----------------
template <int CH, int CL>
__global__ __launch_bounds__(256) void k_scan2(
    const float* __restrict__ delta, const float* __restrict__ xc,
    const float* __restrict__ zb, const float* __restrict__ Bt,
    const float* __restrict__ Ct, const float* __restrict__ A_log,
    const float* __restrict__ D_param,
    const float4* __restrict__ P, const float4* __restrict__ Q,
    float* __restrict__ out) {
  int idx = blockIdx.x * 256 + threadIdx.x;   // B*C*CH*4
  int nl = idx & 3;
  int pc = idx >> 2;
  int chunk = pc % CH;
  int bc = pc / CH;
  int b = bc / C_;
  int c = bc % C_;
  float4 a;
  a.x = -__expf(A_log[c * N_ + nl * 4 + 0]);
  a.y = -__expf(A_log[c * N_ + nl * 4 + 1]);
  a.z = -__expf(A_log[c * N_ + nl * 4 + 2]);
  a.w = -__expf(A_log[c * N_ + nl * 4 + 3]);
  float Dp = D_param[c];
  float4 h = {0.f, 0.f, 0.f, 0.f};
  size_t base = (size_t)bc * CH * 4 + nl;
  for (int k = 0; k < chunk; k++) {
    float4 pk = P[base + (size_t)k * 4];
    float4 qk = Q[base + (size_t)k * 4];
    h.x = pk.x * h.x + qk.x;
    h.y = pk.y * h.y + qk.y;
    h.z = pk.z * h.z + qk.z;
    h.w = pk.w * h.w + qk.w;
  }
  const int l0 = chunk * CL;
  const float* dp = delta + (size_t)bc * L_ + l0;
  const float* xp = xc + (size_t)bc * L_ + l0;
  const float* zp = zb + (size_t)bc * L_ + l0;
  const float* Btp = Bt + ((size_t)b * L_ + l0) * N_ + nl * 4;
  const float* Ctp = Ct + ((size_t)b * L_ + l0) * N_ + nl * 4;
  float* op = out + (size_t)bc * L_ + l0;
#pragma unroll
  for (int l = 0; l < CL; l++) {
    float d = dp[l];
    float xv = xp[l];
    float du = d * xv;
    float4 Bv = *(const float4*)(Btp + (size_t)l * N_);
    float4 Cv = *(const float4*)(Ctp + (size_t)l * N_);
    float ex, ey, ez, ew;
    ex = __expf(d * a.x); ey = __expf(d * a.y);
    ez = __expf(d * a.z); ew = __expf(d * a.w);
    h.x = h.x * ex + du * Bv.x;
    h.y = h.y * ey + du * Bv.y;
    h.z = h.z * ez + du * Bv.z;
    h.w = h.w * ew + du * Bv.w;
    float yv = h.x * Cv.x + h.y * Cv.y + h.z * Cv.z + h.w * Cv.w;
    yv += __shfl_xor(yv, 1);
    yv += __shfl_xor(yv, 2);
    if (nl == 0) {
      float zv = zp[l];
      float sz = zv / (1.f + __expf(-zv));
      op[l] = (yv + xv * Dp) * sz;
    }
  }
}

extern "C" void kernel_launch(void* const* d_in, const int* in_sizes, int n_in,
                              void* d_out, int out_size, void* d_ws, size_t ws_size,
                              hipStream_t stream) {
  const float* hidden    = (const float*)d_in[0];
  const float* in_proj_w = (const float*)d_in[1];
  const float* conv_w    = (const float*)d_in[2];
  const float* conv_b    = (const float*)d_in[3];
  const float* x_proj_w  = (const float*)d_in[4];
  const float* dt_proj_w = (const float*)d_in[5];
  const float* dt_bias   = (const float*)d_in[6];
  const float* A_log     = (const float*)d_in[7];
  const float* D_param   = (const float*)d_in[8];
  float* out = (float*)d_out;

  const size_t NBCL  = (size_t)BSZ * C_ * L_;      // 2408448
  const size_t NDT   = (size_t)BSZ * 96 * L_;      // 150528
  const size_t NBT   = (size_t)BSZ * L_ * N_;      // 25088
  const size_t NPQ1  = (size_t)BSZ * C_ * N_;      // 196608 floats (per chunk)
  const size_t NPART = (size_t)16 * BSZ * L_ * 128; // 3211264
  const size_t NWT   = (size_t)C_ * 128;           // 196608
  const size_t NHID  = (size_t)BSZ * T_ * L_ * D_; // 2408448 elems (hidden)
  const size_t NW1   = (size_t)2 * E_ * D_;        // 73728 elems (in_proj_w)
  float* ws = (float*)d_ws;
  float* xb    = ws;                 // pre-conv x  (reused as delta later)
  float* zb    = xb + NBCL;
  float* xc    = zb + NBCL;          // post-conv x
  float* xdbl  = xc + NBCL;          // dt rows only: B*96*L
  float* BtArr = xdbl + NDT;
  float* CtArr = BtArr + NBT;
  float* Pbuf  = CtArr + NBT;        // big region: hb/wb, part+Wt, later P/Q
  float* delta = xb;                 // reuse: xb dead after conv

  size_t base_floats = 3 * NBCL + NDT + 2 * NBT;
  size_t avail = ws_size / 4 > base_floats ? ws_size / 4 - base_floats : 0;
  bool split_ok = avail >= NPART + NWT;   // also covers bf16 cast region

  // K1: in_proj GEMM
  if (split_ok) {
    ushort_t* hb = (ushort_t*)Pbuf;
    ushort_t* wb = hb + NHID;
    k_cast_bf16<<<(int)((NHID / 8 + 255) / 256), 256, 0, stream>>>(hidden, hb, (int)(NHID / 8));
    k_cast_bf16<<<(int)((NW1 / 8 + 255) / 256), 256, 0, stream>>>(in_proj_w, wb, (int)(NW1 / 8));
    k_inproj_mfma<<<dim3(196, 4), 256, 0, stream>>>(hb, wb, xb, zb);
  } else {
    k_inproj_f32<<<dim3(98, 3), 256, 0, stream>>>(hidden, in_proj_w, xb, zb);
  }

  // K2: conv + silu
  k_conv<<<(int)(NBCL / 256), 256, 0, stream>>>(xb, conv_w, conv_b, xc);

  // K3: x_dbl GEMM (+ B/C transpose)
  if (split_ok) {
    float* part = Pbuf;
    float* Wt   = Pbuf + NPART;
    k_wtrans<<<(int)(NWT / 256), 256, 0, stream>>>(x_proj_w, Wt);
    k_xdbl_tile<<<dim3(25, 16), 256, 0, stream>>>(xc, Wt, part);
    k_xreduce<<<dim3(49, BSZ), 256, 0, stream>>>(part, xdbl, BtArr, CtArr);
  } else {
    k_xdbl_mono<<<dim3(4, 16, BSZ), 256, 0, stream>>>(xc, x_proj_w, xdbl, BtArr, CtArr);
  }

  // K4: delta GEMM + softplus
  k_delta_gemm<<<dim3(25, 24), 256, 0, stream>>>(xdbl, dt_proj_w, dt_bias, delta);

  // K5: chunked scan
  if (avail >= 2 * NPQ1 * 14) {
    float4* P4 = (float4*)Pbuf;
    float4* Q4 = (float4*)(Pbuf + NPQ1 * 14);
    int nthreads = (int)(BSZ * C_ * 14 * 4);   // 688128
    k_scan1<14, 14><<<nthreads / 256, 256, 0, stream>>>(delta, xc, BtArr, A_log, P4, Q4);
    k_scan2<14, 14><<<nthreads / 256, 256, 0, stream>>>(delta, xc, zb, BtArr, CtArr, A_log, D_param, P4, Q4, out);
  } else if (avail >= 2 * NPQ1 * 7) {
    float4* P4 = (float4*)Pbuf;
    float4* Q4 = (float4*)(Pbuf + NPQ1 * 7);
    int nthreads = (int)(BSZ * C_ * 7 * 4);    // 344064
    k_scan1<7, 28><<<nthreads / 256, 256, 0, stream>>>(delta, xc, BtArr, A_log, P4, Q4);
    k_scan2<7, 28><<<nthreads / 256, 256, 0, stream>>>(delta, xc, zb, BtArr, CtArr, A_log, D_param, P4, Q4, out);
  } else {
    float4* P4 = (float4*)Pbuf;
    float4* Q4 = (float4*)(Pbuf + NPQ1 * 2);
    int nthreads = (int)(BSZ * C_ * 2 * 4);    // 98304
    k_scan1<2, 98><<<nthreads / 256, 256, 0, stream>>>(delta, xc, BtArr, A_log, P4, Q4);
    k_scan2<2, 98><<<nthreads / 256, 256, 0, stream>>>(delta, xc, zb, BtArr, CtArr, A_log, D_param, P4, Q4, out);
  }
}